// Round 1
// baseline (478.174 us; speedup 1.0000x reference)
//
#include <hip/hip_runtime.h>
#include <stdint.h>

#define DEVFN __device__ __forceinline__

typedef short s16x8 __attribute__((ext_vector_type(8)));
typedef __bf16 bf16x8 __attribute__((ext_vector_type(8)));
typedef float fx4 __attribute__((ext_vector_type(4)));

// Problem constants (fixed by the reference)
constexpr int SEQ = 8192, DIM = 1280, HEADS = 16, HD = 80;
constexpr int NIMG = 32, CH = 256;       // chunk length per image
constexpr int NQKV = 3840;               // 3*DIM
constexpr int HDP = 96;                  // head_dim padded to multiple of 32 for MFMA K

DEVFN unsigned short f2bf(float f) {
  union { float f; unsigned u; } v; v.f = f;
  unsigned r = v.u + 0x7FFFu + ((v.u >> 16) & 1u);  // RNE
  return (unsigned short)(r >> 16);
}

DEVFN fx4 mfma16(s16x8 a, s16x8 b, fx4 c) {
  return __builtin_amdgcn_mfma_f32_16x16x32_bf16(
      __builtin_bit_cast(bf16x8, a), __builtin_bit_cast(bf16x8, b), c, 0, 0, 0);
}

DEVFN void gload_lds16(const void* g, void* l) {
  // global -> LDS direct, 16B per lane; LDS dest must be wave-uniform base (+lane*16 implicit)
  __builtin_amdgcn_global_load_lds(
      (__attribute__((address_space(1))) void*)(uintptr_t)g,
      (__attribute__((address_space(3))) void*)l, 16, 0, 0);
}

// ---------------- f32 -> bf16 cast, 4 elems/thread ----------------
__global__ __launch_bounds__(256) void cast_bf16_kernel(const float* __restrict__ in,
                                                        unsigned short* __restrict__ out,
                                                        int n4) {
  int i = blockIdx.x * 256 + threadIdx.x;
  if (i >= n4) return;
  float4 v = ((const float4*)in)[i];
  ushort4 o;
  o.x = f2bf(v.x); o.y = f2bf(v.y); o.z = f2bf(v.z); o.w = f2bf(v.w);
  ((ushort4*)out)[i] = o;
}

// ---------------- transpose + cast: T[n][k] = W[k][n], bf16 out ----------------
__global__ __launch_bounds__(256) void transpose_cast_kernel(const float* __restrict__ W,
                                                             unsigned short* __restrict__ T,
                                                             int K, int N) {
  __shared__ float tile[32][33];
  const int tx = threadIdx.x & 31, ty = threadIdx.x >> 5;  // 32x8
  const int n0 = blockIdx.x * 32, k0 = blockIdx.y * 32;
#pragma unroll
  for (int i = 0; i < 4; i++) {
    int r = ty + i * 8;
    tile[r][tx] = W[(size_t)(k0 + r) * N + n0 + tx];
  }
  __syncthreads();
#pragma unroll
  for (int i = 0; i < 4; i++) {
    int r = ty + i * 8;
    T[(size_t)(n0 + r) * K + k0 + tx] = f2bf(tile[tx][r]);
  }
}

// ---------------- GEMM: C[m][n] = sum_k A[m][k]*Bt[n][k] + bias[n], f32 out ----------------
// A, Bt bf16 row-major; 128x128 C tile, BK=32, global_load_lds staging, 16x16x32 MFMA.
__global__ __launch_bounds__(256) void gemm_bt_bias(const unsigned short* __restrict__ A,
                                                    const unsigned short* __restrict__ Bt,
                                                    const float* __restrict__ bias,
                                                    float* __restrict__ C,
                                                    int M, int N, int K) {
  __shared__ __attribute__((aligned(16))) unsigned short As[128 * 32];
  __shared__ __attribute__((aligned(16))) unsigned short Bs[128 * 32];
  const int tid = threadIdx.x;
  const int lane = tid & 63;
  const int w = tid >> 6;             // wave 0..3
  const int wm = w >> 1, wn = w & 1;  // 2x2 wave grid, each 64x64
  const int lrow = lane & 15, lq = lane >> 4;
  const int m0 = blockIdx.y * 128, n0 = blockIdx.x * 128;

  // staging: chunk e covers tile elements e*8..e*8+7 of [128][32]; e0/e1 per thread
  const int e0 = tid, e1 = tid + 256;
  const int r0 = e0 >> 2, c0 = (e0 & 3) * 8;
  const int r1 = e1 >> 2, c1 = (e1 & 3) * 8;
  char* AsC = (char*)As;
  char* BsC = (char*)Bs;
  char* lbA0 = AsC + w * 1024;           // wave-uniform LDS bases
  char* lbA1 = AsC + 4096 + w * 1024;
  char* lbB0 = BsC + w * 1024;
  char* lbB1 = BsC + 4096 + w * 1024;

  fx4 acc[4][4] = {};

  for (int k0 = 0; k0 < K; k0 += 32) {
    __syncthreads();
    gload_lds16(A + (size_t)(m0 + r0) * K + k0 + c0, lbA0);
    gload_lds16(A + (size_t)(m0 + r1) * K + k0 + c1, lbA1);
    gload_lds16(Bt + (size_t)(n0 + r0) * K + k0 + c0, lbB0);
    gload_lds16(Bt + (size_t)(n0 + r1) * K + k0 + c1, lbB1);
    __syncthreads();

    s16x8 a[4], b[4];
#pragma unroll
    for (int i = 0; i < 4; i++)
      a[i] = *(const s16x8*)&As[(wm * 64 + i * 16 + lrow) * 32 + lq * 8];
#pragma unroll
    for (int j = 0; j < 4; j++)
      b[j] = *(const s16x8*)&Bs[(wn * 64 + j * 16 + lrow) * 32 + lq * 8];
#pragma unroll
    for (int i = 0; i < 4; i++)
#pragma unroll
      for (int j = 0; j < 4; j++)
        acc[i][j] = mfma16(a[i], b[j], acc[i][j]);
  }

#pragma unroll
  for (int i = 0; i < 4; i++) {
    const int row_base = m0 + wm * 64 + i * 16 + lq * 4;
#pragma unroll
    for (int j = 0; j < 4; j++) {
      const int col = n0 + wn * 64 + j * 16 + lrow;
      const float bv = bias[col];
#pragma unroll
      for (int r = 0; r < 4; r++)
        C[(size_t)(row_base + r) * N + col] = acc[i][j][r] + bv;
    }
  }
}

// ---------------- RoPE + repack: qkv f32 -> Qb/Kb [nh][256][96] bf16 (pad 0), Vt [nh][80][256] ----------------
__global__ __launch_bounds__(256) void rope_prep_kernel(const float* __restrict__ qkv,
                                                        const float* __restrict__ cosb,
                                                        const float* __restrict__ sinb,
                                                        unsigned short* __restrict__ Qb,
                                                        unsigned short* __restrict__ Kb,
                                                        unsigned short* __restrict__ Vt) {
  __shared__ unsigned short vt[256][88];  // [l][d], padded a bit
  const int tid = threadIdx.x;
  const int h = blockIdx.x & 15, n = blockIdx.x >> 4;
  const int nh = n * 16 + h;
  for (int idx = tid; idx < 256 * 80; idx += 256) {
    const int l = idx / 80, d = idx % 80;
    const int s = n * 256 + l;
    const float* row = qkv + (size_t)s * NQKV;
    const float c = cosb[s * 80 + d], sn = sinb[s * 80 + d];
    const float qv = row[h * 80 + d];
    const float qp = (d < 40) ? -row[h * 80 + d + 40] : row[h * 80 + d - 40];
    Qb[((size_t)nh * 256 + l) * HDP + d] = f2bf(qv * c + qp * sn);
    const float kv = row[DIM + h * 80 + d];
    const float kp = (d < 40) ? -row[DIM + h * 80 + d + 40] : row[DIM + h * 80 + d - 40];
    Kb[((size_t)nh * 256 + l) * HDP + d] = f2bf(kv * c + kp * sn);
    vt[l][d] = f2bf(row[2 * DIM + h * 80 + d]);
  }
  // zero the pad columns 80..95
  for (int idx = tid; idx < 256 * 16; idx += 256) {
    const int l = idx >> 4, dp = 80 + (idx & 15);
    Qb[((size_t)nh * 256 + l) * HDP + dp] = 0;
    Kb[((size_t)nh * 256 + l) * HDP + dp] = 0;
  }
  __syncthreads();
  for (int idx = tid; idx < 80 * 256; idx += 256) {
    const int d = idx >> 8, l = idx & 255;
    Vt[((size_t)nh * 80 + d) * 256 + l] = vt[l][d];
  }
}

// ---------------- attention: per (img,head,64-row q-tile), full 256-key softmax ----------------
__global__ __launch_bounds__(256) void attn_kernel(const unsigned short* __restrict__ Qb,
                                                   const unsigned short* __restrict__ Kb,
                                                   const unsigned short* __restrict__ Vt,
                                                   unsigned short* __restrict__ Ob) {
  __shared__ __attribute__((aligned(16))) char smem[61440];
  unsigned short* Qs = (unsigned short*)smem;             // [64][96]   12KB (phase 1)
  unsigned short* Ks = (unsigned short*)(smem + 12288);   // [256][96]  48KB (phase 1)
  unsigned short* Ps = (unsigned short*)smem;             // [64][256]  32KB (phase 2)
  unsigned short* Vs = (unsigned short*)(smem + 32768);   // [32][256]  16KB (phase 2)

  const int tid = threadIdx.x;
  const int lane = tid & 63, w = tid >> 6;
  const int lrow = lane & 15, lq = lane >> 4;
  const int qt = blockIdx.x, h = blockIdx.y, n = blockIdx.z;
  const int nh = n * 16 + h;

  // stage Q (64x96) and K (256x96), both contiguous in global
  const int4* gQ = (const int4*)(Qb + ((size_t)nh * 256 + qt * 64) * HDP);
  const int4* gK = (const int4*)(Kb + (size_t)nh * 256 * HDP);
  int4* sQ = (int4*)Qs;
  int4* sK = (int4*)Ks;
#pragma unroll
  for (int i = 0; i < 3; i++) sQ[tid + i * 256] = gQ[tid + i * 256];
#pragma unroll
  for (int i = 0; i < 12; i++) sK[tid + i * 256] = gK[tid + i * 256];
  __syncthreads();

  // QK^T: wave w owns rows w*16..w*16+15, all 16 key tiles
  fx4 acc[16] = {};
#pragma unroll
  for (int k0 = 0; k0 < HDP; k0 += 32) {
    s16x8 a = *(const s16x8*)&Qs[(w * 16 + lrow) * HDP + k0 + lq * 8];
#pragma unroll
    for (int t = 0; t < 16; t++) {
      s16x8 b = *(const s16x8*)&Ks[(t * 16 + lrow) * HDP + k0 + lq * 8];
      acc[t] = mfma16(a, b, acc[t]);
    }
  }

  // softmax over 256 keys, rows are wave-local (row = lq*4 + r within strip)
  const float kscale = 0.11180339887498949f * 1.4426950408889634f;  // 80^-0.5 * log2(e)
  float mx[4] = {-1e30f, -1e30f, -1e30f, -1e30f};
#pragma unroll
  for (int t = 0; t < 16; t++)
#pragma unroll
    for (int r = 0; r < 4; r++) mx[r] = fmaxf(mx[r], acc[t][r]);
#pragma unroll
  for (int r = 0; r < 4; r++) {
    mx[r] = fmaxf(mx[r], __shfl_xor(mx[r], 1));
    mx[r] = fmaxf(mx[r], __shfl_xor(mx[r], 2));
    mx[r] = fmaxf(mx[r], __shfl_xor(mx[r], 4));
    mx[r] = fmaxf(mx[r], __shfl_xor(mx[r], 8));
  }
  float sm[4] = {0.f, 0.f, 0.f, 0.f};
#pragma unroll
  for (int t = 0; t < 16; t++)
#pragma unroll
    for (int r = 0; r < 4; r++) {
      float e = exp2f((acc[t][r] - mx[r]) * kscale);
      acc[t][r] = e;
      sm[r] += e;
    }
#pragma unroll
  for (int r = 0; r < 4; r++) {
    sm[r] += __shfl_xor(sm[r], 1);
    sm[r] += __shfl_xor(sm[r], 2);
    sm[r] += __shfl_xor(sm[r], 4);
    sm[r] += __shfl_xor(sm[r], 8);
  }
  float inv[4];
#pragma unroll
  for (int r = 0; r < 4; r++) inv[r] = 1.f / sm[r];

  __syncthreads();  // all waves done reading Qs/Ks before P overwrites them
#pragma unroll
  for (int t = 0; t < 16; t++)
#pragma unroll
    for (int r = 0; r < 4; r++)
      Ps[(w * 16 + lq * 4 + r) * 256 + t * 16 + lrow] = f2bf(acc[t][r] * inv[r]);

  // P @ V in 3 head-dim chunks (32,32,16); V streamed as Vt[d][key]
  const size_t vbase = (size_t)nh * 80 * 256;
  const int d0_arr[3] = {0, 32, 64};
  const int nt_arr[3] = {2, 2, 1};
#pragma unroll
  for (int c = 0; c < 3; c++) {
    const int d0 = d0_arr[c], nt = nt_arr[c];
    __syncthreads();  // previous chunk's MFMA reads done before Vs overwrite; P writes done (c==0)
    const int nchunks = nt * 16 * 256 * 2 / 16;  // 16B chunks
    const int4* gV = (const int4*)(Vt + vbase + (size_t)d0 * 256);
    int4* sV = (int4*)Vs;
    for (int i = tid; i < nchunks; i += 256) sV[i] = gV[i];
    __syncthreads();

    fx4 acc2[2] = {};
#pragma unroll
    for (int k0 = 0; k0 < 256; k0 += 32) {
      s16x8 a = *(const s16x8*)&Ps[(w * 16 + lrow) * 256 + k0 + lq * 8];
#pragma unroll
      for (int j = 0; j < 2; j++) {
        if (j < nt) {
          s16x8 b = *(const s16x8*)&Vs[(j * 16 + lrow) * 256 + k0 + lq * 8];
          acc2[j] = mfma16(a, b, acc2[j]);
        }
      }
    }
    const int srow = n * 256 + qt * 64 + w * 16 + lq * 4;
#pragma unroll
    for (int j = 0; j < 2; j++) {
      if (j < nt) {
        const int col = h * 80 + d0 + j * 16 + lrow;
#pragma unroll
        for (int r = 0; r < 4; r++)
          Ob[(size_t)(srow + r) * DIM + col] = f2bf(acc2[j][r]);
      }
    }
  }
}

// ---------------- launch ----------------
extern "C" void kernel_launch(void* const* d_in, const int* in_sizes, int n_in,
                              void* d_out, int out_size, void* d_ws, size_t ws_size,
                              hipStream_t stream) {
  const float* hidden = (const float*)d_in[0];
  // d_in[1] = cu_seqlens: layout is fixed (32 chunks of 256), unused
  const float* cosb = (const float*)d_in[2];
  const float* sinb = (const float*)d_in[3];
  const float* w_qkv = (const float*)d_in[4];
  const float* b_qkv = (const float*)d_in[5];
  const float* w_proj = (const float*)d_in[6];
  const float* b_proj = (const float*)d_in[7];
  float* out = (float*)d_out;

  // workspace layout (bytes)
  char* ws = (char*)d_ws;
  constexpr size_t QKV_B  = (size_t)SEQ * NQKV * 4;          // 125,829,120 f32 qkv
  constexpr size_t HB_B   = (size_t)SEQ * DIM * 2;           //  20,971,520 hidden bf16
  constexpr size_t WQT_B  = (size_t)NQKV * DIM * 2;          //   9,830,400 w_qkv^T bf16
  constexpr size_t WPT_B  = (size_t)DIM * DIM * 2;           //   3,276,800 w_proj^T bf16
  constexpr size_t QB_B   = (size_t)SEQ * HEADS * HDP * 2 / 16 * 16; // 25,165,824 (exact)
  constexpr size_t VT_B   = (size_t)SEQ * DIM * 2;           //  20,971,520 Vt bf16
  size_t off = 0;
  float* qkv = (float*)(ws + off);
  unsigned short* Ob = (unsigned short*)(ws + off);          // alias qkv (live after prep)
  off += QKV_B;
  unsigned short* hb = (unsigned short*)(ws + off);    off += HB_B;
  unsigned short* wqkvT = (unsigned short*)(ws + off); off += WQT_B;
  unsigned short* wprojT = (unsigned short*)(ws + off); off += WPT_B;
  unsigned short* Qb = (unsigned short*)(ws + off);    off += QB_B;
  unsigned short* Kb = (unsigned short*)(ws + off);    off += QB_B;
  unsigned short* Vt = (unsigned short*)(ws + off);    off += VT_B;
  if (ws_size < off) return;  // workspace too small -> fail loudly via absmax

  // 1. cast hidden to bf16
  cast_bf16_kernel<<<dim3((SEQ * DIM / 4 + 255) / 256), dim3(256), 0, stream>>>(
      hidden, hb, SEQ * DIM / 4);
  // 2. transpose-cast weights
  transpose_cast_kernel<<<dim3(NQKV / 32, DIM / 32), dim3(256), 0, stream>>>(
      w_qkv, wqkvT, DIM, NQKV);
  transpose_cast_kernel<<<dim3(DIM / 32, DIM / 32), dim3(256), 0, stream>>>(
      w_proj, wprojT, DIM, DIM);
  // 3. QKV GEMM (+bias), f32 out
  gemm_bt_bias<<<dim3(NQKV / 128, SEQ / 128), dim3(256), 0, stream>>>(
      hb, wqkvT, b_qkv, qkv, SEQ, NQKV, DIM);
  // 4. RoPE + repack
  rope_prep_kernel<<<dim3(NIMG * HEADS), dim3(256), 0, stream>>>(
      qkv, cosb, sinb, Qb, Kb, Vt);
  // 5. attention
  attn_kernel<<<dim3(4, HEADS, NIMG), dim3(256), 0, stream>>>(Qb, Kb, Vt, Ob);
  // 6. proj GEMM (+bias) -> d_out
  gemm_bt_bias<<<dim3(DIM / 128, SEQ / 128), dim3(256), 0, stream>>>(
      Ob, wprojT, b_proj, out, SEQ, DIM, DIM);
}

// Round 2
// 395.903 us; speedup vs baseline: 1.2078x; 1.2078x over previous
//
#include <hip/hip_runtime.h>
#include <stdint.h>

#define DEVFN __device__ __forceinline__

typedef short s16x8 __attribute__((ext_vector_type(8)));
typedef __bf16 bf16x8 __attribute__((ext_vector_type(8)));
typedef float fx4 __attribute__((ext_vector_type(4)));

// Problem constants (fixed by the reference)
constexpr int SEQ = 8192, DIM = 1280, HEADS = 16;
constexpr int NIMG = 32;
constexpr int NQKV = 3840;               // 3*DIM
constexpr int HDP = 96;                  // head_dim padded to multiple of 32 for MFMA K

DEVFN unsigned short f2bf(float f) {
  union { float f; unsigned u; } v; v.f = f;
  unsigned r = v.u + 0x7FFFu + ((v.u >> 16) & 1u);  // RNE
  return (unsigned short)(r >> 16);
}
DEVFN float bf2f(unsigned short u) {
  union { unsigned u; float f; } v; v.u = ((unsigned)u) << 16;
  return v.f;
}

DEVFN fx4 mfma16(s16x8 a, s16x8 b, fx4 c) {
  return __builtin_amdgcn_mfma_f32_16x16x32_bf16(
      __builtin_bit_cast(bf16x8, a), __builtin_bit_cast(bf16x8, b), c, 0, 0, 0);
}

DEVFN void gload_lds16(const void* g, void* l) {
  // global -> LDS direct, 16B per lane; LDS dest = wave-uniform base + lane*16
  __builtin_amdgcn_global_load_lds(
      (__attribute__((address_space(1))) void*)(uintptr_t)g,
      (__attribute__((address_space(3))) void*)l, 16, 0, 0);
}

// ---------------- f32 -> bf16 cast, 4 elems/thread ----------------
__global__ __launch_bounds__(256) void cast_bf16_kernel(const float* __restrict__ in,
                                                        unsigned short* __restrict__ out,
                                                        int n4) {
  int i = blockIdx.x * 256 + threadIdx.x;
  if (i >= n4) return;
  float4 v = ((const float4*)in)[i];
  ushort4 o;
  o.x = f2bf(v.x); o.y = f2bf(v.y); o.z = f2bf(v.z); o.w = f2bf(v.w);
  ((ushort4*)out)[i] = o;
}

// ---------------- transpose + cast: T[n][k] = W[k][n], bf16 out ----------------
__global__ __launch_bounds__(256) void transpose_cast_kernel(const float* __restrict__ W,
                                                             unsigned short* __restrict__ T,
                                                             int K, int N) {
  __shared__ float tile[32][33];
  const int tx = threadIdx.x & 31, ty = threadIdx.x >> 5;  // 32x8
  const int n0 = blockIdx.x * 32, k0 = blockIdx.y * 32;
#pragma unroll
  for (int i = 0; i < 4; i++) {
    int r = ty + i * 8;
    tile[r][tx] = W[(size_t)(k0 + r) * N + n0 + tx];
  }
  __syncthreads();
#pragma unroll
  for (int i = 0; i < 4; i++) {
    int r = ty + i * 8;
    T[(size_t)(n0 + r) * K + k0 + tx] = f2bf(tile[tx][r]);
  }
}

// ---------------- GEMM: C[m][n] = sum_k A[m][k]*Bt[n][k] + bias[n] ----------------
// A, Bt bf16 row-major; 128x128 C tile, BK=32, global_load_lds staging, 16x16x32 MFMA.
// GROUP_M swizzle for L2 reuse of B panels. Output f32 or bf16.
template <bool BF16OUT>
__global__ __launch_bounds__(256) void gemm_bt_bias(const unsigned short* __restrict__ A,
                                                    const unsigned short* __restrict__ Bt,
                                                    const float* __restrict__ bias,
                                                    void* __restrict__ Cv,
                                                    int M, int N, int K) {
  __shared__ __attribute__((aligned(16))) unsigned short As[128 * 32];
  __shared__ __attribute__((aligned(16))) unsigned short Bs[128 * 32];
  const int tid = threadIdx.x;
  const int lane = tid & 63;
  const int w = tid >> 6;             // wave 0..3
  const int wm = w >> 1, wn = w & 1;  // 2x2 wave grid, each 64x64
  const int lrow = lane & 15, lq = lane >> 4;

  // GROUP_M swizzle: consecutive pids walk M within a group -> share B panel
  const int GROUP_M = 16;
  const int pid = blockIdx.y * gridDim.x + blockIdx.x;
  const int nig = GROUP_M * gridDim.x;
  const int gid = pid / nig;
  const int first = gid * GROUP_M;
  const int gsz = min(GROUP_M, (int)gridDim.y - first);
  const int bm = first + (pid % nig) % gsz;
  const int bn = (pid % nig) / gsz;
  const int m0 = bm * 128, n0 = bn * 128;

  // staging: chunk e covers tile elements e*8..e*8+7 of [128][32]
  const int e0 = tid, e1 = tid + 256;
  const int r0 = e0 >> 2, c0 = (e0 & 3) * 8;
  const int r1 = e1 >> 2, c1 = (e1 & 3) * 8;
  char* AsC = (char*)As;
  char* BsC = (char*)Bs;
  char* lbA0 = AsC + w * 1024;           // wave-uniform LDS bases
  char* lbA1 = AsC + 4096 + w * 1024;
  char* lbB0 = BsC + w * 1024;
  char* lbB1 = BsC + 4096 + w * 1024;

  fx4 acc[4][4] = {};

  for (int k0 = 0; k0 < K; k0 += 32) {
    __syncthreads();
    gload_lds16(A + (size_t)(m0 + r0) * K + k0 + c0, lbA0);
    gload_lds16(A + (size_t)(m0 + r1) * K + k0 + c1, lbA1);
    gload_lds16(Bt + (size_t)(n0 + r0) * K + k0 + c0, lbB0);
    gload_lds16(Bt + (size_t)(n0 + r1) * K + k0 + c1, lbB1);
    __syncthreads();

    s16x8 a[4], b[4];
#pragma unroll
    for (int i = 0; i < 4; i++)
      a[i] = *(const s16x8*)&As[(wm * 64 + i * 16 + lrow) * 32 + lq * 8];
#pragma unroll
    for (int j = 0; j < 4; j++)
      b[j] = *(const s16x8*)&Bs[(wn * 64 + j * 16 + lrow) * 32 + lq * 8];
#pragma unroll
    for (int i = 0; i < 4; i++)
#pragma unroll
      for (int j = 0; j < 4; j++)
        acc[i][j] = mfma16(a[i], b[j], acc[i][j]);
  }

#pragma unroll
  for (int i = 0; i < 4; i++) {
    const int row_base = m0 + wm * 64 + i * 16 + lq * 4;
#pragma unroll
    for (int j = 0; j < 4; j++) {
      const int col = n0 + wn * 64 + j * 16 + lrow;
      const float bv = bias[col];
#pragma unroll
      for (int r = 0; r < 4; r++) {
        const float val = acc[i][j][r] + bv;
        if (BF16OUT)
          ((unsigned short*)Cv)[(size_t)(row_base + r) * N + col] = f2bf(val);
        else
          ((float*)Cv)[(size_t)(row_base + r) * N + col] = val;
      }
    }
  }
}

// ---------------- RoPE + repack ----------------
// qkvb bf16 [SEQ][3840] -> Qb/Kb [nh][256][96] bf16 (pad 0), Vt [nh][80][256] bf16.
// Block handles 64 seq rows x 8 heads; cos/sin staged once (f32) in LDS.
__global__ __launch_bounds__(256) void rope_prep2(const unsigned short* __restrict__ qkvb,
                                                  const float* __restrict__ cosb,
                                                  const float* __restrict__ sinb,
                                                  unsigned short* __restrict__ Qb,
                                                  unsigned short* __restrict__ Kb,
                                                  unsigned short* __restrict__ Vt) {
  __shared__ float cosS[64 * 80];                                    // 20480 B
  __shared__ float sinS[64 * 80];                                    // 20480 B
  __shared__ __attribute__((aligned(16))) unsigned short tile[64 * 80];  // 10240 B
  const int t = threadIdx.x;
  const int rq = blockIdx.x, hh = blockIdx.y, n = blockIdx.z;
  const int s0 = n * 256 + rq * 64;

  // stage cos/sin: 64 rows x 20 float4 each; thread t -> row t>>2, 5 chunks
  {
    const int row = t >> 2, cbase = (t & 3) * 5;
    const float4* gc = (const float4*)(cosb + (size_t)(s0 + row) * 80);
    const float4* gs = (const float4*)(sinb + (size_t)(s0 + row) * 80);
    float4* lc = (float4*)&cosS[row * 80];
    float4* ls = (float4*)&sinS[row * 80];
#pragma unroll
    for (int j = 0; j < 5; j++) {
      lc[cbase + j] = gc[cbase + j];
      ls[cbase + j] = gs[cbase + j];
    }
  }

  for (int hi = 0; hi < 8; hi++) {
    const int h = hh * 8 + hi;
    const int nh = n * 16 + h;

    // ---- Q then K: stage 64x80 tile, rope, write padded 96 ----
#pragma unroll
    for (int qk = 0; qk < 2; qk++) {
      const int colbase = qk * DIM + h * 80;
      unsigned short* dst = qk ? Kb : Qb;
      __syncthreads();  // protect tile from previous use
      for (int idx = t; idx < 640; idx += 256) {
        const int row = idx / 10, c = idx % 10;
        *(int4*)&tile[row * 80 + c * 8] =
            *(const int4*)(qkvb + (size_t)(s0 + row) * NQKV + colbase + c * 8);
      }
      __syncthreads();
      for (int idx = t; idx < 768; idx += 256) {
        const int row = idx / 12, c = idx % 12;
        int4 ov = {0, 0, 0, 0};
        if (c < 10) {
          const int d0 = c * 8;
          s16x8 xv = *(const s16x8*)&tile[row * 80 + d0];
          s16x8 pv = (d0 < 40) ? *(const s16x8*)&tile[row * 80 + d0 + 40]
                               : *(const s16x8*)&tile[row * 80 + d0 - 40];
          const float sgn = (d0 < 40) ? -1.f : 1.f;
          unsigned short o[8];
#pragma unroll
          for (int j = 0; j < 8; j++) {
            const float x = bf2f((unsigned short)xv[j]);
            const float p = sgn * bf2f((unsigned short)pv[j]);
            o[j] = f2bf(x * cosS[row * 80 + d0 + j] + p * sinS[row * 80 + d0 + j]);
          }
          ov = *(const int4*)o;
        }
        *(int4*)(dst + ((size_t)nh * 256 + rq * 64 + row) * HDP + c * 8) = ov;
      }
    }

    // ---- V: stage, then transposed write Vt[nh][d][s] ----
    __syncthreads();
    for (int idx = t; idx < 640; idx += 256) {
      const int row = idx / 10, c = idx % 10;
      *(int4*)&tile[row * 80 + c * 8] =
          *(const int4*)(qkvb + (size_t)(s0 + row) * NQKV + 2 * DIM + h * 80 + c * 8);
    }
    __syncthreads();
    for (int idx = t; idx < 640; idx += 256) {
      const int d = idx >> 3, sc = idx & 7;  // 80 d-rows x 8 chunks of 8 keys
      unsigned short o[8];
#pragma unroll
      for (int j = 0; j < 8; j++) o[j] = tile[(sc * 8 + j) * 80 + d];
      *(int4*)(Vt + ((size_t)nh * 80 + d) * 256 + rq * 64 + sc * 8) = *(const int4*)o;
    }
  }
}

// ---------------- attention: block per (img, head, 64-row q-tile) ----------------
// K staged in LDS via global_load_lds; Q fragments + V fragments direct from global;
// P (padded stride 264) aliased over K. 3 barriers total.
__global__ __launch_bounds__(256) void attn_kernel(const unsigned short* __restrict__ Qb,
                                                   const unsigned short* __restrict__ Kb,
                                                   const unsigned short* __restrict__ Vt,
                                                   unsigned short* __restrict__ Ob) {
  __shared__ __attribute__((aligned(16))) char smem[49152];
  unsigned short* Ks = (unsigned short*)smem;  // [256][96]  48 KB (phase 1)
  unsigned short* Ps = (unsigned short*)smem;  // [64][264]  33.8 KB (phase 2, aliased)

  const int tid = threadIdx.x;
  const int lane = tid & 63, w = tid >> 6;
  const int lrow = lane & 15, lq = lane >> 4;
  const int qt = blockIdx.x, h = blockIdx.y, n = blockIdx.z;
  const int nh = n * 16 + h;

  // stage K (256x96 bf16 = 48 KB), contiguous; wave w covers 12 KB in 12 chunks
  {
    const char* gK = (const char*)(Kb + (size_t)nh * 256 * HDP);
#pragma unroll
    for (int i = 0; i < 12; i++) {
      const int off = (i * 4 + w) * 1024;
      gload_lds16(gK + off + lane * 16, smem + off);
    }
  }

  // Q fragments direct from global (wave w owns q rows w*16..w*16+15)
  s16x8 aq[3];
  {
    const unsigned short* gQ = Qb + ((size_t)nh * 256 + qt * 64 + w * 16 + lrow) * HDP;
#pragma unroll
    for (int c = 0; c < 3; c++) aq[c] = *(const s16x8*)(gQ + c * 32 + lq * 8);
  }
  __syncthreads();

  // QK^T: 16 key tiles x 3 k-chunks
  fx4 acc[16] = {};
#pragma unroll
  for (int c = 0; c < 3; c++) {
#pragma unroll
    for (int t = 0; t < 16; t++) {
      s16x8 b = *(const s16x8*)&Ks[(t * 16 + lrow) * HDP + c * 32 + lq * 8];
      acc[t] = mfma16(aq[c], b, acc[t]);
    }
  }

  // softmax over 256 keys; rows are wave-local (row = lq*4 + r)
  const float kscale = 0.11180339887498949f * 1.4426950408889634f;  // 80^-0.5 * log2e
  float mx[4] = {-1e30f, -1e30f, -1e30f, -1e30f};
#pragma unroll
  for (int t = 0; t < 16; t++)
#pragma unroll
    for (int r = 0; r < 4; r++) mx[r] = fmaxf(mx[r], acc[t][r]);
#pragma unroll
  for (int r = 0; r < 4; r++) {
    mx[r] = fmaxf(mx[r], __shfl_xor(mx[r], 1));
    mx[r] = fmaxf(mx[r], __shfl_xor(mx[r], 2));
    mx[r] = fmaxf(mx[r], __shfl_xor(mx[r], 4));
    mx[r] = fmaxf(mx[r], __shfl_xor(mx[r], 8));
  }
  float sm[4] = {0.f, 0.f, 0.f, 0.f};
#pragma unroll
  for (int t = 0; t < 16; t++)
#pragma unroll
    for (int r = 0; r < 4; r++) {
      float e = exp2f((acc[t][r] - mx[r]) * kscale);
      acc[t][r] = e;
      sm[r] += e;
    }
#pragma unroll
  for (int r = 0; r < 4; r++) {
    sm[r] += __shfl_xor(sm[r], 1);
    sm[r] += __shfl_xor(sm[r], 2);
    sm[r] += __shfl_xor(sm[r], 4);
    sm[r] += __shfl_xor(sm[r], 8);
  }
  float inv[4];
#pragma unroll
  for (int r = 0; r < 4; r++) inv[r] = 1.f / sm[r];

  __syncthreads();  // all waves done reading Ks before Ps overwrites
#pragma unroll
  for (int t = 0; t < 16; t++)
#pragma unroll
    for (int r = 0; r < 4; r++)
      Ps[(w * 16 + lq * 4 + r) * 264 + t * 16 + lrow] = f2bf(acc[t][r] * inv[r]);
  __syncthreads();

  // P @ V: V^T rows (d) direct from global (L2-resident: 40 KB per head)
  const unsigned short* gV = Vt + (size_t)nh * 80 * 256;
  fx4 acc2[5] = {};
#pragma unroll
  for (int kc = 0; kc < 8; kc++) {
    s16x8 a = *(const s16x8*)&Ps[(w * 16 + lrow) * 264 + kc * 32 + lq * 8];
#pragma unroll
    for (int t = 0; t < 5; t++) {
      s16x8 b = *(const s16x8*)(gV + (size_t)(t * 16 + lrow) * 256 + kc * 32 + lq * 8);
      acc2[t] = mfma16(a, b, acc2[t]);
    }
  }

  const int srow = n * 256 + qt * 64 + w * 16 + lq * 4;
#pragma unroll
  for (int t = 0; t < 5; t++) {
    const int col = h * 80 + t * 16 + lrow;
#pragma unroll
    for (int r = 0; r < 4; r++)
      Ob[(size_t)(srow + r) * DIM + col] = f2bf(acc2[t][r]);
  }
}

// ---------------- launch ----------------
extern "C" void kernel_launch(void* const* d_in, const int* in_sizes, int n_in,
                              void* d_out, int out_size, void* d_ws, size_t ws_size,
                              hipStream_t stream) {
  const float* hidden = (const float*)d_in[0];
  // d_in[1] = cu_seqlens: fixed layout (32 chunks of 256), unused
  const float* cosb = (const float*)d_in[2];
  const float* sinb = (const float*)d_in[3];
  const float* w_qkv = (const float*)d_in[4];
  const float* b_qkv = (const float*)d_in[5];
  const float* w_proj = (const float*)d_in[6];
  const float* b_proj = (const float*)d_in[7];
  float* out = (float*)d_out;

  // workspace layout (bytes)
  char* ws = (char*)d_ws;
  constexpr size_t QKV_B = (size_t)SEQ * NQKV * 2;   // 62,914,560 bf16 qkv (aliases Ob)
  constexpr size_t HB_B  = (size_t)SEQ * DIM * 2;    // 20,971,520 hidden bf16
  constexpr size_t WQT_B = (size_t)NQKV * DIM * 2;   //  9,830,400 w_qkv^T bf16
  constexpr size_t WPT_B = (size_t)DIM * DIM * 2;    //  3,276,800 w_proj^T bf16
  constexpr size_t QB_B  = (size_t)NIMG * HEADS * 256 * HDP * 2;  // 25,165,824
  constexpr size_t VT_B  = (size_t)NIMG * HEADS * 80 * 256 * 2;   // 20,971,520
  size_t off = 0;
  unsigned short* qkvb = (unsigned short*)(ws + off);
  unsigned short* Ob = (unsigned short*)(ws + off);  // alias (qkvb dead after rope)
  off += QKV_B;
  unsigned short* hb = (unsigned short*)(ws + off);     off += HB_B;
  unsigned short* wqkvT = (unsigned short*)(ws + off);  off += WQT_B;
  unsigned short* wprojT = (unsigned short*)(ws + off); off += WPT_B;
  unsigned short* Qb = (unsigned short*)(ws + off);     off += QB_B;
  unsigned short* Kb = (unsigned short*)(ws + off);     off += QB_B;
  unsigned short* Vt = (unsigned short*)(ws + off);     off += VT_B;
  if (ws_size < off) return;

  // 1. cast hidden to bf16
  cast_bf16_kernel<<<dim3((SEQ * DIM / 4 + 255) / 256), dim3(256), 0, stream>>>(
      hidden, hb, SEQ * DIM / 4);
  // 2. transpose-cast weights
  transpose_cast_kernel<<<dim3(NQKV / 32, DIM / 32), dim3(256), 0, stream>>>(
      w_qkv, wqkvT, DIM, NQKV);
  transpose_cast_kernel<<<dim3(DIM / 32, DIM / 32), dim3(256), 0, stream>>>(
      w_proj, wprojT, DIM, DIM);
  // 3. QKV GEMM (+bias), bf16 out
  gemm_bt_bias<true><<<dim3(NQKV / 128, SEQ / 128), dim3(256), 0, stream>>>(
      hb, wqkvT, b_qkv, qkvb, SEQ, NQKV, DIM);
  // 4. RoPE + repack
  rope_prep2<<<dim3(4, 2, NIMG), dim3(256), 0, stream>>>(qkvb, cosb, sinb, Qb, Kb, Vt);
  // 5. attention
  attn_kernel<<<dim3(4, HEADS, NIMG), dim3(256), 0, stream>>>(Qb, Kb, Vt, Ob);
  // 6. proj GEMM (+bias) -> d_out (f32)
  gemm_bt_bias<false><<<dim3(DIM / 128, SEQ / 128), dim3(256), 0, stream>>>(
      Ob, wprojT, b_proj, out, SEQ, DIM, DIM);
}

// Round 3
// 375.707 us; speedup vs baseline: 1.2727x; 1.0538x over previous
//
#include <hip/hip_runtime.h>
#include <stdint.h>

#define DEVFN __device__ __forceinline__

typedef short s16x8 __attribute__((ext_vector_type(8)));
typedef __bf16 bf16x8 __attribute__((ext_vector_type(8)));
typedef float fx4 __attribute__((ext_vector_type(4)));

// Problem constants (fixed by the reference)
constexpr int SEQ = 8192, DIM = 1280, HEADS = 16;
constexpr int NIMG = 32;
constexpr int NQKV = 3840;               // 3*DIM
constexpr int HDP = 96;                  // head_dim padded to multiple of 32 for MFMA K

DEVFN unsigned short f2bf(float f) {
  union { float f; unsigned u; } v; v.f = f;
  unsigned r = v.u + 0x7FFFu + ((v.u >> 16) & 1u);  // RNE
  return (unsigned short)(r >> 16);
}
DEVFN float bf2f(unsigned short u) {
  union { unsigned u; float f; } v; v.u = ((unsigned)u) << 16;
  return v.f;
}

DEVFN fx4 mfma16(s16x8 a, s16x8 b, fx4 c) {
  return __builtin_amdgcn_mfma_f32_16x16x32_bf16(
      __builtin_bit_cast(bf16x8, a), __builtin_bit_cast(bf16x8, b), c, 0, 0, 0);
}

DEVFN void gload_lds16(const void* g, void* l) {
  // global -> LDS direct, 16B per lane; LDS dest = wave-uniform base + lane*16
  __builtin_amdgcn_global_load_lds(
      (__attribute__((address_space(1))) void*)(uintptr_t)g,
      (__attribute__((address_space(3))) void*)l, 16, 0, 0);
}

// ---------------- f32 -> bf16 cast, 4 elems/thread ----------------
__global__ __launch_bounds__(256) void cast_bf16_kernel(const float* __restrict__ in,
                                                        unsigned short* __restrict__ out,
                                                        int n4) {
  int i = blockIdx.x * 256 + threadIdx.x;
  if (i >= n4) return;
  float4 v = ((const float4*)in)[i];
  ushort4 o;
  o.x = f2bf(v.x); o.y = f2bf(v.y); o.z = f2bf(v.z); o.w = f2bf(v.w);
  ((ushort4*)out)[i] = o;
}

// ---------------- transpose + cast: T[n][k] = W[k][n], bf16 out ----------------
__global__ __launch_bounds__(256) void transpose_cast_kernel(const float* __restrict__ W,
                                                             unsigned short* __restrict__ T,
                                                             int K, int N) {
  __shared__ float tile[32][33];
  const int tx = threadIdx.x & 31, ty = threadIdx.x >> 5;  // 32x8
  const int n0 = blockIdx.x * 32, k0 = blockIdx.y * 32;
#pragma unroll
  for (int i = 0; i < 4; i++) {
    int r = ty + i * 8;
    tile[r][tx] = W[(size_t)(k0 + r) * N + n0 + tx];
  }
  __syncthreads();
#pragma unroll
  for (int i = 0; i < 4; i++) {
    int r = ty + i * 8;
    T[(size_t)(n0 + r) * K + k0 + tx] = f2bf(tile[tx][r]);
  }
}

// ---------------- GEMM: C[m][n] = sum_k A[m][k]*Bt[n][k] + bias[n] ----------------
// A, Bt bf16 row-major; 128x128 C tile, BK=64, 16x16x32 MFMA.
// LDS layout XOR-swizzled at 16B-chunk granularity: slot(row,c) = row*8 + (c^(row&7)).
// global_load_lds stages it by permuting the per-lane GLOBAL source (LDS dest is
// lane-contiguous by HW); ds_read_b128 then sees 2-way-max bank aliasing (free).
template <bool BF16OUT>
__global__ __launch_bounds__(256) void gemm_bt_bias(const unsigned short* __restrict__ A,
                                                    const unsigned short* __restrict__ Bt,
                                                    const float* __restrict__ bias,
                                                    void* __restrict__ Cv,
                                                    int M, int N, int K) {
  __shared__ __attribute__((aligned(16))) unsigned short As[128 * 64];
  __shared__ __attribute__((aligned(16))) unsigned short Bs[128 * 64];
  const int tid = threadIdx.x;
  const int lane = tid & 63;
  const int w = tid >> 6;             // wave 0..3
  const int wm = w >> 1, wn = w & 1;  // 2x2 wave grid, each 64x64
  const int lrow = lane & 15, lq = lane >> 4;

  // GROUP_M swizzle: consecutive pids walk M within a group -> share B panel
  const int GROUP_M = 16;
  const int pid = blockIdx.y * gridDim.x + blockIdx.x;
  const int nig = GROUP_M * gridDim.x;
  const int gid = pid / nig;
  const int first = gid * GROUP_M;
  const int gsz = min(GROUP_M, (int)gridDim.y - first);
  const int bm = first + (pid % nig) % gsz;
  const int bn = (pid % nig) / gsz;
  const int m0 = bm * 128, n0 = bn * 128;

  // staging: 1024 16B-chunks per matrix per iter; thread covers slots i*256+tid.
  // slot s -> row r = s>>3, holds global chunk c = (s&7) ^ (r&7).
  int srow[4], scol[4];
#pragma unroll
  for (int i = 0; i < 4; i++) {
    const int s = i * 256 + tid;
    const int r = s >> 3;
    srow[i] = r;
    scol[i] = ((s & 7) ^ (r & 7)) * 8;
  }
  char* ldsA[4];
  char* ldsB[4];
#pragma unroll
  for (int i = 0; i < 4; i++) {
    ldsA[i] = (char*)As + i * 4096 + w * 1024;  // wave-uniform bases
    ldsB[i] = (char*)Bs + i * 4096 + w * 1024;
  }

  // ds_read byte offsets (swizzled), fixed across K-loop
  int offA[4][2], offB[4][2];
#pragma unroll
  for (int i = 0; i < 4; i++) {
    const int ra = wm * 64 + i * 16 + lrow;
    const int rb = wn * 64 + i * 16 + lrow;
    offA[i][0] = (ra * 8 + (lq ^ (ra & 7))) * 16;
    offA[i][1] = (ra * 8 + ((lq + 4) ^ (ra & 7))) * 16;
    offB[i][0] = (rb * 8 + (lq ^ (rb & 7))) * 16;
    offB[i][1] = (rb * 8 + ((lq + 4) ^ (rb & 7))) * 16;
  }

  fx4 acc[4][4] = {};

  for (int k0 = 0; k0 < K; k0 += 64) {
    __syncthreads();
#pragma unroll
    for (int i = 0; i < 4; i++) {
      gload_lds16(A + (size_t)(m0 + srow[i]) * K + k0 + scol[i], ldsA[i]);
      gload_lds16(Bt + (size_t)(n0 + srow[i]) * K + k0 + scol[i], ldsB[i]);
    }
    __syncthreads();

#pragma unroll
    for (int h = 0; h < 2; h++) {
      s16x8 a[4], b[4];
#pragma unroll
      for (int i = 0; i < 4; i++) a[i] = *(const s16x8*)((char*)As + offA[i][h]);
#pragma unroll
      for (int j = 0; j < 4; j++) b[j] = *(const s16x8*)((char*)Bs + offB[j][h]);
#pragma unroll
      for (int i = 0; i < 4; i++)
#pragma unroll
        for (int j = 0; j < 4; j++)
          acc[i][j] = mfma16(a[i], b[j], acc[i][j]);
    }
  }

#pragma unroll
  for (int i = 0; i < 4; i++) {
    const int row_base = m0 + wm * 64 + i * 16 + lq * 4;
#pragma unroll
    for (int j = 0; j < 4; j++) {
      const int col = n0 + wn * 64 + j * 16 + lrow;
      const float bv = bias[col];
#pragma unroll
      for (int r = 0; r < 4; r++) {
        const float val = acc[i][j][r] + bv;
        if (BF16OUT)
          ((unsigned short*)Cv)[(size_t)(row_base + r) * N + col] = f2bf(val);
        else
          ((float*)Cv)[(size_t)(row_base + r) * N + col] = val;
      }
    }
  }
}

// ---------------- RoPE + repack, one (64-row, head) tile per block ----------------
// qkvb bf16 [SEQ][3840] -> Qb/Kb [nh][256][96] bf16 (pad 0), Vt [nh][80][256] bf16.
// cos/sin read direct from global (L2-shared across the 16 head-blocks per row-tile).
__global__ __launch_bounds__(256) void rope_prep3(const unsigned short* __restrict__ qkvb,
                                                  const float* __restrict__ cosb,
                                                  const float* __restrict__ sinb,
                                                  unsigned short* __restrict__ Qb,
                                                  unsigned short* __restrict__ Kb,
                                                  unsigned short* __restrict__ Vt) {
  __shared__ __attribute__((aligned(16))) unsigned short tile[64 * 80];  // 10 KB
  const int t = threadIdx.x;
  const int rq = blockIdx.x, h = blockIdx.y, n = blockIdx.z;
  const int s0 = n * 256 + rq * 64;
  const int nh = n * 16 + h;

  // ---- Q then K: stage 64x80 tile, rope, write padded 96 ----
#pragma unroll
  for (int qk = 0; qk < 2; qk++) {
    const int colbase = qk * DIM + h * 80;
    unsigned short* dst = qk ? Kb : Qb;
    if (qk) __syncthreads();  // protect tile from previous use
    for (int idx = t; idx < 640; idx += 256) {
      const int row = idx / 10, c = idx % 10;
      *(int4*)&tile[row * 80 + c * 8] =
          *(const int4*)(qkvb + (size_t)(s0 + row) * NQKV + colbase + c * 8);
    }
    __syncthreads();
    for (int idx = t; idx < 768; idx += 256) {
      const int row = idx / 12, c = idx % 12;
      int4 ov = {0, 0, 0, 0};
      if (c < 10) {
        const int d0 = c * 8;
        s16x8 xv = *(const s16x8*)&tile[row * 80 + d0];
        s16x8 pv = (d0 < 40) ? *(const s16x8*)&tile[row * 80 + d0 + 40]
                             : *(const s16x8*)&tile[row * 80 + d0 - 40];
        const float sgn = (d0 < 40) ? -1.f : 1.f;
        const float4 c0 = *(const float4*)(cosb + (size_t)(s0 + row) * 80 + d0);
        const float4 c1 = *(const float4*)(cosb + (size_t)(s0 + row) * 80 + d0 + 4);
        const float4 s0v = *(const float4*)(sinb + (size_t)(s0 + row) * 80 + d0);
        const float4 s1v = *(const float4*)(sinb + (size_t)(s0 + row) * 80 + d0 + 4);
        const float cc[8] = {c0.x, c0.y, c0.z, c0.w, c1.x, c1.y, c1.z, c1.w};
        const float ss[8] = {s0v.x, s0v.y, s0v.z, s0v.w, s1v.x, s1v.y, s1v.z, s1v.w};
        unsigned short o[8];
#pragma unroll
        for (int j = 0; j < 8; j++) {
          const float x = bf2f((unsigned short)xv[j]);
          const float p = sgn * bf2f((unsigned short)pv[j]);
          o[j] = f2bf(x * cc[j] + p * ss[j]);
        }
        ov = *(const int4*)o;
      }
      *(int4*)(dst + ((size_t)nh * 256 + rq * 64 + row) * HDP + c * 8) = ov;
    }
  }

  // ---- V: stage, then transposed write Vt[nh][d][s] ----
  __syncthreads();
  for (int idx = t; idx < 640; idx += 256) {
    const int row = idx / 10, c = idx % 10;
    *(int4*)&tile[row * 80 + c * 8] =
        *(const int4*)(qkvb + (size_t)(s0 + row) * NQKV + 2 * DIM + h * 80 + c * 8);
  }
  __syncthreads();
  for (int idx = t; idx < 640; idx += 256) {
    const int d = idx >> 3, sc = idx & 7;  // 80 d-rows x 8 chunks of 8 keys
    unsigned short o[8];
#pragma unroll
    for (int j = 0; j < 8; j++) o[j] = tile[(sc * 8 + j) * 80 + d];
    *(int4*)(Vt + ((size_t)nh * 80 + d) * 256 + rq * 64 + sc * 8) = *(const int4*)o;
  }
}

// ---------------- attention: block per (img, head, 64-row q-tile) ----------------
// K staged in LDS via global_load_lds; Q fragments + V fragments direct from global;
// P (padded stride 264) aliased over K. 3 barriers total.
__global__ __launch_bounds__(256) void attn_kernel(const unsigned short* __restrict__ Qb,
                                                   const unsigned short* __restrict__ Kb,
                                                   const unsigned short* __restrict__ Vt,
                                                   unsigned short* __restrict__ Ob) {
  __shared__ __attribute__((aligned(16))) char smem[49152];
  unsigned short* Ks = (unsigned short*)smem;  // [256][96]  48 KB (phase 1)
  unsigned short* Ps = (unsigned short*)smem;  // [64][264]  33.8 KB (phase 2, aliased)

  const int tid = threadIdx.x;
  const int lane = tid & 63, w = tid >> 6;
  const int lrow = lane & 15, lq = lane >> 4;
  const int qt = blockIdx.x, h = blockIdx.y, n = blockIdx.z;
  const int nh = n * 16 + h;

  // stage K (256x96 bf16 = 48 KB), contiguous; wave w covers 12 KB in 12 chunks
  {
    const char* gK = (const char*)(Kb + (size_t)nh * 256 * HDP);
#pragma unroll
    for (int i = 0; i < 12; i++) {
      const int off = (i * 4 + w) * 1024;
      gload_lds16(gK + off + lane * 16, smem + off);
    }
  }

  // Q fragments direct from global (wave w owns q rows w*16..w*16+15)
  s16x8 aq[3];
  {
    const unsigned short* gQ = Qb + ((size_t)nh * 256 + qt * 64 + w * 16 + lrow) * HDP;
#pragma unroll
    for (int c = 0; c < 3; c++) aq[c] = *(const s16x8*)(gQ + c * 32 + lq * 8);
  }
  __syncthreads();

  // QK^T: 16 key tiles x 3 k-chunks
  fx4 acc[16] = {};
#pragma unroll
  for (int c = 0; c < 3; c++) {
#pragma unroll
    for (int t = 0; t < 16; t++) {
      s16x8 b = *(const s16x8*)&Ks[(t * 16 + lrow) * HDP + c * 32 + lq * 8];
      acc[t] = mfma16(aq[c], b, acc[t]);
    }
  }

  // softmax over 256 keys; rows are wave-local (row = lq*4 + r)
  const float kscale = 0.11180339887498949f * 1.4426950408889634f;  // 80^-0.5 * log2e
  float mx[4] = {-1e30f, -1e30f, -1e30f, -1e30f};
#pragma unroll
  for (int t = 0; t < 16; t++)
#pragma unroll
    for (int r = 0; r < 4; r++) mx[r] = fmaxf(mx[r], acc[t][r]);
#pragma unroll
  for (int r = 0; r < 4; r++) {
    mx[r] = fmaxf(mx[r], __shfl_xor(mx[r], 1));
    mx[r] = fmaxf(mx[r], __shfl_xor(mx[r], 2));
    mx[r] = fmaxf(mx[r], __shfl_xor(mx[r], 4));
    mx[r] = fmaxf(mx[r], __shfl_xor(mx[r], 8));
  }
  float sm[4] = {0.f, 0.f, 0.f, 0.f};
#pragma unroll
  for (int t = 0; t < 16; t++)
#pragma unroll
    for (int r = 0; r < 4; r++) {
      float e = exp2f((acc[t][r] - mx[r]) * kscale);
      acc[t][r] = e;
      sm[r] += e;
    }
#pragma unroll
  for (int r = 0; r < 4; r++) {
    sm[r] += __shfl_xor(sm[r], 1);
    sm[r] += __shfl_xor(sm[r], 2);
    sm[r] += __shfl_xor(sm[r], 4);
    sm[r] += __shfl_xor(sm[r], 8);
  }
  float inv[4];
#pragma unroll
  for (int r = 0; r < 4; r++) inv[r] = 1.f / sm[r];

  __syncthreads();  // all waves done reading Ks before Ps overwrites
#pragma unroll
  for (int t = 0; t < 16; t++)
#pragma unroll
    for (int r = 0; r < 4; r++)
      Ps[(w * 16 + lq * 4 + r) * 264 + t * 16 + lrow] = f2bf(acc[t][r] * inv[r]);
  __syncthreads();

  // P @ V: V^T rows (d) direct from global (L2-resident: 40 KB per head)
  const unsigned short* gV = Vt + (size_t)nh * 80 * 256;
  fx4 acc2[5] = {};
#pragma unroll
  for (int kc = 0; kc < 8; kc++) {
    s16x8 a = *(const s16x8*)&Ps[(w * 16 + lrow) * 264 + kc * 32 + lq * 8];
#pragma unroll
    for (int t = 0; t < 5; t++) {
      s16x8 b = *(const s16x8*)(gV + (size_t)(t * 16 + lrow) * 256 + kc * 32 + lq * 8);
      acc2[t] = mfma16(a, b, acc2[t]);
    }
  }

  const int srow = n * 256 + qt * 64 + w * 16 + lq * 4;
#pragma unroll
  for (int t = 0; t < 5; t++) {
    const int col = h * 80 + t * 16 + lrow;
#pragma unroll
    for (int r = 0; r < 4; r++)
      Ob[(size_t)(srow + r) * DIM + col] = f2bf(acc2[t][r]);
  }
}

// ---------------- launch ----------------
extern "C" void kernel_launch(void* const* d_in, const int* in_sizes, int n_in,
                              void* d_out, int out_size, void* d_ws, size_t ws_size,
                              hipStream_t stream) {
  const float* hidden = (const float*)d_in[0];
  // d_in[1] = cu_seqlens: fixed layout (32 chunks of 256), unused
  const float* cosb = (const float*)d_in[2];
  const float* sinb = (const float*)d_in[3];
  const float* w_qkv = (const float*)d_in[4];
  const float* b_qkv = (const float*)d_in[5];
  const float* w_proj = (const float*)d_in[6];
  const float* b_proj = (const float*)d_in[7];
  float* out = (float*)d_out;

  // workspace layout (bytes)
  char* ws = (char*)d_ws;
  constexpr size_t QKV_B = (size_t)SEQ * NQKV * 2;   // 62,914,560 bf16 qkv (aliases Ob)
  constexpr size_t HB_B  = (size_t)SEQ * DIM * 2;    // 20,971,520 hidden bf16
  constexpr size_t WQT_B = (size_t)NQKV * DIM * 2;   //  9,830,400 w_qkv^T bf16
  constexpr size_t WPT_B = (size_t)DIM * DIM * 2;    //  3,276,800 w_proj^T bf16
  constexpr size_t QB_B  = (size_t)NIMG * HEADS * 256 * HDP * 2;  // 25,165,824
  constexpr size_t VT_B  = (size_t)NIMG * HEADS * 80 * 256 * 2;   // 20,971,520
  size_t off = 0;
  unsigned short* qkvb = (unsigned short*)(ws + off);
  unsigned short* Ob = (unsigned short*)(ws + off);  // alias (qkvb dead after rope)
  off += QKV_B;
  unsigned short* hb = (unsigned short*)(ws + off);     off += HB_B;
  unsigned short* wqkvT = (unsigned short*)(ws + off);  off += WQT_B;
  unsigned short* wprojT = (unsigned short*)(ws + off); off += WPT_B;
  unsigned short* Qb = (unsigned short*)(ws + off);     off += QB_B;
  unsigned short* Kb = (unsigned short*)(ws + off);     off += QB_B;
  unsigned short* Vt = (unsigned short*)(ws + off);     off += VT_B;
  if (ws_size < off) return;

  // 1. cast hidden to bf16
  cast_bf16_kernel<<<dim3((SEQ * DIM / 4 + 255) / 256), dim3(256), 0, stream>>>(
      hidden, hb, SEQ * DIM / 4);
  // 2. transpose-cast weights
  transpose_cast_kernel<<<dim3(NQKV / 32, DIM / 32), dim3(256), 0, stream>>>(
      w_qkv, wqkvT, DIM, NQKV);
  transpose_cast_kernel<<<dim3(DIM / 32, DIM / 32), dim3(256), 0, stream>>>(
      w_proj, wprojT, DIM, DIM);
  // 3. QKV GEMM (+bias), bf16 out
  gemm_bt_bias<true><<<dim3(NQKV / 128, SEQ / 128), dim3(256), 0, stream>>>(
      hb, wqkvT, b_qkv, qkvb, SEQ, NQKV, DIM);
  // 4. RoPE + repack
  rope_prep3<<<dim3(4, HEADS, NIMG), dim3(256), 0, stream>>>(qkvb, cosb, sinb, Qb, Kb, Vt);
  // 5. attention
  attn_kernel<<<dim3(4, HEADS, NIMG), dim3(256), 0, stream>>>(Qb, Kb, Vt, Ob);
  // 6. proj GEMM (+bias) -> d_out (f32)
  gemm_bt_bias<false><<<dim3(DIM / 128, SEQ / 128), dim3(256), 0, stream>>>(
      Ob, wprojT, b_proj, out, SEQ, DIM, DIM);
}

// Round 4
// 359.485 us; speedup vs baseline: 1.3302x; 1.0451x over previous
//
#include <hip/hip_runtime.h>
#include <stdint.h>

#define DEVFN __device__ __forceinline__

typedef short s16x8 __attribute__((ext_vector_type(8)));
typedef __bf16 bf16x8 __attribute__((ext_vector_type(8)));
typedef float fx4 __attribute__((ext_vector_type(4)));

// Problem constants (fixed by the reference)
constexpr int SEQ = 8192, DIM = 1280, HEADS = 16;
constexpr int NIMG = 32;
constexpr int NQKV = 3840;               // 3*DIM

DEVFN unsigned short f2bf(float f) {
  union { float f; unsigned u; } v; v.f = f;
  unsigned r = v.u + 0x7FFFu + ((v.u >> 16) & 1u);  // RNE
  return (unsigned short)(r >> 16);
}
DEVFN float bf2f(unsigned short u) {
  union { unsigned u; float f; } v; v.u = ((unsigned)u) << 16;
  return v.f;
}

DEVFN fx4 mfma16(s16x8 a, s16x8 b, fx4 c) {
  return __builtin_amdgcn_mfma_f32_16x16x32_bf16(
      __builtin_bit_cast(bf16x8, a), __builtin_bit_cast(bf16x8, b), c, 0, 0, 0);
}

DEVFN void gload_lds16(const void* g, void* l) {
  // global -> LDS direct, 16B per lane; LDS dest = wave-uniform base + lane*16
  __builtin_amdgcn_global_load_lds(
      (__attribute__((address_space(1))) void*)(uintptr_t)g,
      (__attribute__((address_space(3))) void*)l, 16, 0, 0);
}

// ---------------- f32 -> bf16 cast, 4 elems/thread ----------------
__global__ __launch_bounds__(256) void cast_bf16_kernel(const float* __restrict__ in,
                                                        unsigned short* __restrict__ out,
                                                        int n4) {
  int i = blockIdx.x * 256 + threadIdx.x;
  if (i >= n4) return;
  float4 v = ((const float4*)in)[i];
  ushort4 o;
  o.x = f2bf(v.x); o.y = f2bf(v.y); o.z = f2bf(v.z); o.w = f2bf(v.w);
  ((ushort4*)out)[i] = o;
}

// ---------------- transpose + cast: T[n][k] = W[k][n], bf16 out ----------------
__global__ __launch_bounds__(256) void transpose_cast_kernel(const float* __restrict__ W,
                                                             unsigned short* __restrict__ T,
                                                             int K, int N) {
  __shared__ float tile[32][33];
  const int tx = threadIdx.x & 31, ty = threadIdx.x >> 5;  // 32x8
  const int n0 = blockIdx.x * 32, k0 = blockIdx.y * 32;
#pragma unroll
  for (int i = 0; i < 4; i++) {
    int r = ty + i * 8;
    tile[r][tx] = W[(size_t)(k0 + r) * N + n0 + tx];
  }
  __syncthreads();
#pragma unroll
  for (int i = 0; i < 4; i++) {
    int r = ty + i * 8;
    T[(size_t)(n0 + r) * K + k0 + tx] = f2bf(tile[tx][r]);
  }
}

// ---------------- GEMM: C[m][n] = sum_k A[m][k]*Bt[n][k] + bias[n] ----------------
// A, Bt bf16 row-major; 128x128 C tile, BK=64, 16x16x32 MFMA.
// LDS XOR-swizzled at 16B-chunk granularity: slot(row,c) = row*8 + (c^(row&7)).
template <bool BF16OUT>
__global__ __launch_bounds__(256) void gemm_bt_bias(const unsigned short* __restrict__ A,
                                                    const unsigned short* __restrict__ Bt,
                                                    const float* __restrict__ bias,
                                                    void* __restrict__ Cv,
                                                    int M, int N, int K) {
  __shared__ __attribute__((aligned(16))) unsigned short As[128 * 64];
  __shared__ __attribute__((aligned(16))) unsigned short Bs[128 * 64];
  const int tid = threadIdx.x;
  const int lane = tid & 63;
  const int w = tid >> 6;             // wave 0..3
  const int wm = w >> 1, wn = w & 1;  // 2x2 wave grid, each 64x64
  const int lrow = lane & 15, lq = lane >> 4;

  // GROUP_M swizzle: consecutive pids walk M within a group -> share B panel
  const int GROUP_M = 16;
  const int pid = blockIdx.y * gridDim.x + blockIdx.x;
  const int nig = GROUP_M * gridDim.x;
  const int gid = pid / nig;
  const int first = gid * GROUP_M;
  const int gsz = min(GROUP_M, (int)gridDim.y - first);
  const int bm = first + (pid % nig) % gsz;
  const int bn = (pid % nig) / gsz;
  const int m0 = bm * 128, n0 = bn * 128;

  int srow[4], scol[4];
#pragma unroll
  for (int i = 0; i < 4; i++) {
    const int s = i * 256 + tid;
    const int r = s >> 3;
    srow[i] = r;
    scol[i] = ((s & 7) ^ (r & 7)) * 8;
  }
  char* ldsA[4];
  char* ldsB[4];
#pragma unroll
  for (int i = 0; i < 4; i++) {
    ldsA[i] = (char*)As + i * 4096 + w * 1024;  // wave-uniform bases
    ldsB[i] = (char*)Bs + i * 4096 + w * 1024;
  }

  int offA[4][2], offB[4][2];
#pragma unroll
  for (int i = 0; i < 4; i++) {
    const int ra = wm * 64 + i * 16 + lrow;
    const int rb = wn * 64 + i * 16 + lrow;
    offA[i][0] = (ra * 8 + (lq ^ (ra & 7))) * 16;
    offA[i][1] = (ra * 8 + ((lq + 4) ^ (ra & 7))) * 16;
    offB[i][0] = (rb * 8 + (lq ^ (rb & 7))) * 16;
    offB[i][1] = (rb * 8 + ((lq + 4) ^ (rb & 7))) * 16;
  }

  fx4 acc[4][4] = {};

  for (int k0 = 0; k0 < K; k0 += 64) {
    __syncthreads();
#pragma unroll
    for (int i = 0; i < 4; i++) {
      gload_lds16(A + (size_t)(m0 + srow[i]) * K + k0 + scol[i], ldsA[i]);
      gload_lds16(Bt + (size_t)(n0 + srow[i]) * K + k0 + scol[i], ldsB[i]);
    }
    __syncthreads();

#pragma unroll
    for (int h = 0; h < 2; h++) {
      s16x8 a[4], b[4];
#pragma unroll
      for (int i = 0; i < 4; i++) a[i] = *(const s16x8*)((char*)As + offA[i][h]);
#pragma unroll
      for (int j = 0; j < 4; j++) b[j] = *(const s16x8*)((char*)Bs + offB[j][h]);
#pragma unroll
      for (int i = 0; i < 4; i++)
#pragma unroll
        for (int j = 0; j < 4; j++)
          acc[i][j] = mfma16(a[i], b[j], acc[i][j]);
    }
  }

#pragma unroll
  for (int i = 0; i < 4; i++) {
    const int row_base = m0 + wm * 64 + i * 16 + lq * 4;
#pragma unroll
    for (int j = 0; j < 4; j++) {
      const int col = n0 + wn * 64 + j * 16 + lrow;
      const float bv = bias[col];
#pragma unroll
      for (int r = 0; r < 4; r++) {
        const float val = acc[i][j][r] + bv;
        if (BF16OUT)
          ((unsigned short*)Cv)[(size_t)(row_base + r) * N + col] = f2bf(val);
        else
          ((float*)Cv)[(size_t)(row_base + r) * N + col] = val;
      }
    }
  }
}

// ---------------- fused RoPE + attention ----------------
// Block = (head h, img n), 512 threads = 8 waves; wave w owns q-rows w*32..w*32+31.
// LDS regions (147.25 KB total):
//   X  @0      : raw K [256][80] -> rope'd Ks [256][104] (stride 104 = 52 dw = 20 mod 32,
//                2-way bank aliasing = free) -> later P-scratch (8 waves x 16 x 264)
//   Y  @67584  : raw Q [256][80] -> later Vt [80][264] (264 = 132 dw = 4 mod 32, free)
//   RV @109824 : raw V [256][80]
__global__ __launch_bounds__(512, 2) void fused_attn(const unsigned short* __restrict__ qkvb,
                                                     const float* __restrict__ cosb,
                                                     const float* __restrict__ sinb,
                                                     unsigned short* __restrict__ Ob) {
  __shared__ __attribute__((aligned(16))) char smem[150784];
  unsigned short* X = (unsigned short*)smem;
  unsigned short* Y = (unsigned short*)(smem + 67584);
  unsigned short* RV = (unsigned short*)(smem + 109824);

  const int t = threadIdx.x;
  const int lane = t & 63, w = t >> 6;
  const int lrow = lane & 15, lq = lane >> 4;
  const int h = blockIdx.x, n = blockIdx.y;
  const int s0 = n * 256;

  // ---- phase 1: stage raw Q,K,V (each [256][80] bf16, rows 160B) ----
#pragma unroll
  for (int i = 0; i < 5; i++) {
    const int idx = t + i * 512;
    const unsigned r = (unsigned)idx / 10u, c = (unsigned)idx % 10u;
    const size_t g = (size_t)(s0 + r) * NQKV + h * 80 + c * 8;
    *(int4*)&Y[r * 80 + c * 8] = *(const int4*)(qkvb + g);            // Q
    *(int4*)&X[r * 80 + c * 8] = *(const int4*)(qkvb + g + DIM);      // K
    *(int4*)&RV[r * 80 + c * 8] = *(const int4*)(qkvb + g + 2 * DIM); // V
  }
  __syncthreads();  // B1

  // ---- phase 2 (read-only): K rope -> regs; Q rope -> A-fragments ----
  unsigned short kout[5][8];
  int kro[5], kco[5];
#pragma unroll
  for (int i = 0; i < 5; i++) {
    const int idx = t + i * 512;
    const unsigned r = (unsigned)idx / 10u, c = (unsigned)idx % 10u;
    kro[i] = r; kco[i] = c;
    s16x8 xv = *(const s16x8*)&X[r * 80 + c * 8];
    const unsigned cp = (c < 5) ? c + 5 : c - 5;  // partner chunk (+-40 elems)
    s16x8 pv = *(const s16x8*)&X[r * 80 + cp * 8];
    const float sgn = (c < 5) ? -1.f : 1.f;
    const float* cf = cosb + (size_t)(s0 + r) * 80 + c * 8;
    const float* sf = sinb + (size_t)(s0 + r) * 80 + c * 8;
#pragma unroll
    for (int j = 0; j < 8; j++)
      kout[i][j] = f2bf(bf2f((unsigned short)xv[j]) * cf[j] +
                        sgn * bf2f((unsigned short)pv[j]) * sf[j]);
  }

  s16x8 aq[2][3];
#pragma unroll
  for (int rt = 0; rt < 2; rt++) {
#pragma unroll
    for (int c = 0; c < 3; c++) {
      const int row = w * 32 + rt * 16 + lrow;
      const int d0 = c * 32 + lq * 8;
      s16x8 fr = {};
      if (d0 < 80) {
        s16x8 xv = *(const s16x8*)&Y[row * 80 + d0];
        const int dp = (d0 < 40) ? d0 + 40 : d0 - 40;
        s16x8 pv = *(const s16x8*)&Y[row * 80 + dp];
        const float sgn = (d0 < 40) ? -1.f : 1.f;
        const float* cf = cosb + (size_t)(s0 + row) * 80 + d0;
        const float* sf = sinb + (size_t)(s0 + row) * 80 + d0;
#pragma unroll
        for (int j = 0; j < 8; j++)
          fr[j] = (short)f2bf(bf2f((unsigned short)xv[j]) * cf[j] +
                              sgn * bf2f((unsigned short)pv[j]) * sf[j]);
      }
      aq[rt][c] = fr;
    }
  }
  __syncthreads();  // B2

  // ---- phase 3: write rope'd K at stride 104 (+ zero pad cols 80..95) ----
#pragma unroll
  for (int i = 0; i < 5; i++)
    *(int4*)&X[kro[i] * 104 + kco[i] * 8] = *(const int4*)kout[i];
  {
    const int r = t >> 1, wh = t & 1;
    const int4 z = {0, 0, 0, 0};
    *(int4*)&X[r * 104 + 80 + wh * 8] = z;
  }
  __syncthreads();  // B3

  // ---- QK^T: 2 row-tiles x 16 col-tiles, K = 96 (3 chunks of 32) ----
  fx4 acc[2][16] = {};
#pragma unroll
  for (int c = 0; c < 3; c++) {
#pragma unroll
    for (int ct = 0; ct < 16; ct++) {
      s16x8 b = *(const s16x8*)&X[(ct * 16 + lrow) * 104 + c * 32 + lq * 8];
      acc[0][ct] = mfma16(aq[0][c], b, acc[0][ct]);
      acc[1][ct] = mfma16(aq[1][c], b, acc[1][ct]);
    }
  }

  // ---- softmax (rows wave-local: row = rt*16 + lq*4 + r) ----
  const float kscale = 0.11180339887498949f * 1.4426950408889634f;  // 80^-0.5 * log2e
  float inv[2][4];
#pragma unroll
  for (int rt = 0; rt < 2; rt++) {
    float mx[4] = {-1e30f, -1e30f, -1e30f, -1e30f};
#pragma unroll
    for (int ct = 0; ct < 16; ct++)
#pragma unroll
      for (int r = 0; r < 4; r++) mx[r] = fmaxf(mx[r], acc[rt][ct][r]);
#pragma unroll
    for (int r = 0; r < 4; r++) {
      mx[r] = fmaxf(mx[r], __shfl_xor(mx[r], 1));
      mx[r] = fmaxf(mx[r], __shfl_xor(mx[r], 2));
      mx[r] = fmaxf(mx[r], __shfl_xor(mx[r], 4));
      mx[r] = fmaxf(mx[r], __shfl_xor(mx[r], 8));
    }
    float sm[4] = {0.f, 0.f, 0.f, 0.f};
#pragma unroll
    for (int ct = 0; ct < 16; ct++)
#pragma unroll
      for (int r = 0; r < 4; r++) {
        float e = exp2f((acc[rt][ct][r] - mx[r]) * kscale);
        acc[rt][ct][r] = e;
        sm[r] += e;
      }
#pragma unroll
    for (int r = 0; r < 4; r++) {
      sm[r] += __shfl_xor(sm[r], 1);
      sm[r] += __shfl_xor(sm[r], 2);
      sm[r] += __shfl_xor(sm[r], 4);
      sm[r] += __shfl_xor(sm[r], 8);
      inv[rt][r] = 1.f / sm[r];
    }
  }
  __syncthreads();  // B4 (all waves done reading Ks; X becomes P-scratch)

  // ---- V transpose: RV [256][80] -> Vt (Y) [80][264] ----
#pragma unroll
  for (int i = 0; i < 5; i++) {
    const int idx = t + i * 512;            // 2560 = 80 d-rows x 32 key-chunks
    const int d = idx >> 5, c = idx & 31;
    unsigned short o[8];
#pragma unroll
    for (int j = 0; j < 8; j++) o[j] = RV[(c * 8 + j) * 80 + d];
    *(int4*)&Y[d * 264 + c * 8] = *(const int4*)o;
  }

  // ---- P (rt=0) to per-wave scratch ----
  unsigned short* Pw = X + w * 4224;  // 16 rows x 264 elems
#pragma unroll
  for (int ct = 0; ct < 16; ct++)
#pragma unroll
    for (int r = 0; r < 4; r++)
      Pw[(lq * 4 + r) * 264 + ct * 16 + lrow] = f2bf(acc[0][ct][r] * inv[0][r]);
  __syncthreads();  // B5 (Vt complete before any PV b-read)

  // ---- PV + output, two 16-row sweeps ----
#pragma unroll
  for (int rt = 0; rt < 2; rt++) {
    if (rt == 1) {
      // own-wave scratch reuse; within-wave LDS ordering via compiler waitcnt
#pragma unroll
      for (int ct = 0; ct < 16; ct++)
#pragma unroll
        for (int r = 0; r < 4; r++)
          Pw[(lq * 4 + r) * 264 + ct * 16 + lrow] = f2bf(acc[1][ct][r] * inv[1][r]);
    }
    fx4 acc2[5] = {};
#pragma unroll
    for (int kc = 0; kc < 8; kc++) {
      s16x8 a = *(const s16x8*)&Pw[lrow * 264 + kc * 32 + lq * 8];
#pragma unroll
      for (int tt = 0; tt < 5; tt++) {
        s16x8 b = *(const s16x8*)&Y[(tt * 16 + lrow) * 264 + kc * 32 + lq * 8];
        acc2[tt] = mfma16(a, b, acc2[tt]);
      }
    }
    const int srow = s0 + w * 32 + rt * 16 + lq * 4;
#pragma unroll
    for (int tt = 0; tt < 5; tt++) {
      const int col = h * 80 + tt * 16 + lrow;
#pragma unroll
      for (int r = 0; r < 4; r++)
        Ob[(size_t)(srow + r) * DIM + col] = f2bf(acc2[tt][r]);
    }
  }
}

// ---------------- launch ----------------
extern "C" void kernel_launch(void* const* d_in, const int* in_sizes, int n_in,
                              void* d_out, int out_size, void* d_ws, size_t ws_size,
                              hipStream_t stream) {
  const float* hidden = (const float*)d_in[0];
  // d_in[1] = cu_seqlens: fixed layout (32 chunks of 256), unused
  const float* cosb = (const float*)d_in[2];
  const float* sinb = (const float*)d_in[3];
  const float* w_qkv = (const float*)d_in[4];
  const float* b_qkv = (const float*)d_in[5];
  const float* w_proj = (const float*)d_in[6];
  const float* b_proj = (const float*)d_in[7];
  float* out = (float*)d_out;

  // workspace layout (bytes)
  char* ws = (char*)d_ws;
  constexpr size_t QKV_B = (size_t)SEQ * NQKV * 2;  // 62,914,560 bf16 qkv
  constexpr size_t HB_B = (size_t)SEQ * DIM * 2;    // 20,971,520 hidden bf16
  constexpr size_t WQT_B = (size_t)NQKV * DIM * 2;  //  9,830,400 w_qkv^T bf16
  constexpr size_t WPT_B = (size_t)DIM * DIM * 2;   //  3,276,800 w_proj^T bf16
  constexpr size_t OB_B = (size_t)SEQ * DIM * 2;    // 20,971,520 attn out bf16
  size_t off = 0;
  unsigned short* qkvb = (unsigned short*)(ws + off);   off += QKV_B;
  unsigned short* hb = (unsigned short*)(ws + off);     off += HB_B;
  unsigned short* wqkvT = (unsigned short*)(ws + off);  off += WQT_B;
  unsigned short* wprojT = (unsigned short*)(ws + off); off += WPT_B;
  unsigned short* Ob = (unsigned short*)(ws + off);     off += OB_B;
  if (ws_size < off) return;

  // 1. cast hidden to bf16
  cast_bf16_kernel<<<dim3((SEQ * DIM / 4 + 255) / 256), dim3(256), 0, stream>>>(
      hidden, hb, SEQ * DIM / 4);
  // 2. transpose-cast weights
  transpose_cast_kernel<<<dim3(NQKV / 32, DIM / 32), dim3(256), 0, stream>>>(
      w_qkv, wqkvT, DIM, NQKV);
  transpose_cast_kernel<<<dim3(DIM / 32, DIM / 32), dim3(256), 0, stream>>>(
      w_proj, wprojT, DIM, DIM);
  // 3. QKV GEMM (+bias), bf16 out
  gemm_bt_bias<true><<<dim3(NQKV / 128, SEQ / 128), dim3(256), 0, stream>>>(
      hb, wqkvT, b_qkv, qkvb, SEQ, NQKV, DIM);
  // 4. fused RoPE + attention -> Ob
  fused_attn<<<dim3(HEADS, NIMG), dim3(512), 0, stream>>>(qkvb, cosb, sinb, Ob);
  // 5. proj GEMM (+bias) -> d_out (f32)
  gemm_bt_bias<false><<<dim3(DIM / 128, SEQ / 128), dim3(256), 0, stream>>>(
      Ob, wprojT, b_proj, out, SEQ, DIM, DIM);
}

// Round 5
// 311.555 us; speedup vs baseline: 1.5348x; 1.1538x over previous
//
#include <hip/hip_runtime.h>
#include <stdint.h>

#define DEVFN __device__ __forceinline__

typedef short s16x8 __attribute__((ext_vector_type(8)));
typedef __bf16 bf16x8 __attribute__((ext_vector_type(8)));
typedef float fx4 __attribute__((ext_vector_type(4)));

// Problem constants (fixed by the reference)
constexpr int SEQ = 8192, DIM = 1280, HEADS = 16;
constexpr int NIMG = 32;
constexpr int NQKV = 3840;  // 3*DIM

DEVFN unsigned short f2bf(float f) {
  union { float f; unsigned u; } v; v.f = f;
  unsigned r = v.u + 0x7FFFu + ((v.u >> 16) & 1u);  // RNE
  return (unsigned short)(r >> 16);
}
DEVFN float bf2f(unsigned short u) {
  union { unsigned u; float f; } v; v.u = ((unsigned)u) << 16;
  return v.f;
}

DEVFN fx4 mfma16(s16x8 a, s16x8 b, fx4 c) {
  return __builtin_amdgcn_mfma_f32_16x16x32_bf16(
      __builtin_bit_cast(bf16x8, a), __builtin_bit_cast(bf16x8, b), c, 0, 0, 0);
}

DEVFN void gload_lds16(const void* g, void* l) {
  // global -> LDS direct, 16B per lane; LDS dest = wave-uniform base + lane*16
  __builtin_amdgcn_global_load_lds(
      (__attribute__((address_space(1))) void*)(uintptr_t)g,
      (__attribute__((address_space(3))) void*)l, 16, 0, 0);
}

// ---------------- f32 -> bf16 cast, 4 elems/thread ----------------
__global__ __launch_bounds__(256) void cast_bf16_kernel(const float* __restrict__ in,
                                                        unsigned short* __restrict__ out,
                                                        int n4) {
  int i = blockIdx.x * 256 + threadIdx.x;
  if (i >= n4) return;
  float4 v = ((const float4*)in)[i];
  ushort4 o;
  o.x = f2bf(v.x); o.y = f2bf(v.y); o.z = f2bf(v.z); o.w = f2bf(v.w);
  ((ushort4*)out)[i] = o;
}

// ---------------- transpose + cast: T[n][k] = W[k][n], bf16 out ----------------
__global__ __launch_bounds__(256) void transpose_cast_kernel(const float* __restrict__ W,
                                                             unsigned short* __restrict__ T,
                                                             int K, int N) {
  __shared__ float tile[32][33];
  const int tx = threadIdx.x & 31, ty = threadIdx.x >> 5;  // 32x8
  const int n0 = blockIdx.x * 32, k0 = blockIdx.y * 32;
#pragma unroll
  for (int i = 0; i < 4; i++) {
    int r = ty + i * 8;
    tile[r][tx] = W[(size_t)(k0 + r) * N + n0 + tx];
  }
  __syncthreads();
#pragma unroll
  for (int i = 0; i < 4; i++) {
    int r = ty + i * 8;
    T[(size_t)(n0 + r) * K + k0 + tx] = f2bf(tile[tx][r]);
  }
}

// ---------------- mega kernel: QKV GEMM + bias + RoPE + attention ----------------
// Block = (img n, head h), 512 threads = 8 waves in a 4x2 grid (wm rows, wn cols).
// Stage A (256 hidden rows x BK=128) and B (240 w_qkvT rows + 16 pad, x128) with the
// XOR-16 chunk swizzle; 10 K-iters, 128 MFMA/wave/iter; epilogue scatters acc+bias
// into the raw Q/K/V LDS tiles; then rope + QK^T + softmax + PV as before.
// LDS aliasing (150784 B): GEMM staging As@0(64K) Bs@64K(64K) dead before
// X@0 (raw K -> Ks[256][104] -> P-scratch), Y@67584 (raw Q -> Vt[80][264]),
// RV@109824 (raw V) are written (barrier after K-loop).
__global__ __launch_bounds__(512, 2) void mega_attn(const unsigned short* __restrict__ hb,
                                                    const unsigned short* __restrict__ wqkvT,
                                                    const float* __restrict__ b_qkv,
                                                    const float* __restrict__ cosb,
                                                    const float* __restrict__ sinb,
                                                    unsigned short* __restrict__ Ob) {
  __shared__ __attribute__((aligned(16))) char smem[150784];
  unsigned short* X = (unsigned short*)smem;
  unsigned short* Y = (unsigned short*)(smem + 67584);
  unsigned short* RV = (unsigned short*)(smem + 109824);
  char* AsC = smem;            // [256][128] bf16, swizzled
  char* BsC = smem + 65536;    // [256][128] bf16, swizzled

  const int t = threadIdx.x;
  const int lane = t & 63, w = t >> 6;
  const int lrow = lane & 15, lq = lane >> 4;
  const int n = blockIdx.x, h = blockIdx.y;
  const int s0 = n * 256;
  const int wm = w >> 1, wn = w & 1;

  // ---- staging geometry (slot s = i*512 + t; r = s>>4 = tr+32i; chunk = (s&15)^(r&15)) ----
  const int tr = t >> 4;
  const int scN = ((t & 15) ^ (tr & 15)) * 8;  // global col offset (elems), same for all i
  const unsigned short* pA0 = hb + (size_t)(s0 + tr) * 1280 + scN;
  const unsigned short* pB[8];
#pragma unroll
  for (int i = 0; i < 8; i++) {
    const int r = tr + 32 * i;
    const int rr = r < 240 ? r : 239;  // pad rows clamp (cols 240..255 never read)
    const int sgm = (rr >= 160) ? 2 : (rr >= 80 ? 1 : 0);
    const int grow = sgm * DIM + h * 80 + (rr - sgm * 80);
    pB[i] = wqkvT + (size_t)grow * 1280 + scN;
  }

  // fragment geometry: row&15 == lrow for all tiles (16-stride tiles)
  const int baseA = (wm * 64 + lrow) * 256;   // byte row base in As (row*16 chunks*16B)
  const int baseB = (wn * 128 + lrow) * 256;  // byte row base in Bs

  fx4 acc[4][8] = {};

  for (int k0 = 0; k0 < 1280; k0 += 128) {
    __syncthreads();
#pragma unroll
    for (int i = 0; i < 8; i++) {
      gload_lds16(pA0 + (size_t)i * 32 * 1280 + k0, AsC + i * 8192 + w * 1024);
      gload_lds16(pB[i] + k0, BsC + i * 8192 + w * 1024);
    }
    __syncthreads();
#pragma unroll
    for (int kq4 = 0; kq4 < 4; kq4++) {
      const int xq = ((lq + kq4 * 4) ^ lrow) * 16;  // swizzled chunk byte offset
      s16x8 a[4], b[8];
#pragma unroll
      for (int i = 0; i < 4; i++) a[i] = *(const s16x8*)(AsC + baseA + i * 4096 + xq);
#pragma unroll
      for (int j = 0; j < 8; j++) b[j] = *(const s16x8*)(BsC + baseB + j * 4096 + xq);
#pragma unroll
      for (int i = 0; i < 4; i++)
#pragma unroll
        for (int j = 0; j < 8; j++)
          acc[i][j] = mfma16(a[i], b[j], acc[i][j]);
    }
  }
  __syncthreads();  // all MFMA fragment reads done before staging regions become Q/K/V

  // ---- epilogue scatter: acc + bias -> raw Q (Y), K (X), V (RV), each [256][80] ----
#pragma unroll
  for (int j = 0; j < 8; j++) {
    const int col = wn * 128 + j * 16 + lrow;
    if (col < 240) {
      const int sgm = (col >= 160) ? 2 : (col >= 80 ? 1 : 0);
      const int d = col - sgm * 80;
      const float bv = b_qkv[sgm * DIM + h * 80 + d];
      unsigned short* dst = (sgm == 0) ? Y : (sgm == 1) ? X : RV;
#pragma unroll
      for (int i = 0; i < 4; i++) {
        const int row = wm * 64 + i * 16 + lq * 4;
#pragma unroll
        for (int r = 0; r < 4; r++)
          dst[(row + r) * 80 + d] = f2bf(acc[i][j][r] + bv);
      }
    }
  }
  __syncthreads();  // B1: raw Q/K/V complete

  // ---- K rope -> regs; Q rope -> A-fragments (wave w owns q-rows w*32..w*32+31) ----
  unsigned short kout[5][8];
  int kro[5], kco[5];
#pragma unroll
  for (int i = 0; i < 5; i++) {
    const int idx = t + i * 512;
    const unsigned r = (unsigned)idx / 10u, c = (unsigned)idx % 10u;
    kro[i] = r; kco[i] = c;
    s16x8 xv = *(const s16x8*)&X[r * 80 + c * 8];
    const unsigned cp = (c < 5) ? c + 5 : c - 5;  // partner chunk (+-40 elems)
    s16x8 pv = *(const s16x8*)&X[r * 80 + cp * 8];
    const float sgn = (c < 5) ? -1.f : 1.f;
    const float* cf = cosb + (size_t)(s0 + r) * 80 + c * 8;
    const float* sf = sinb + (size_t)(s0 + r) * 80 + c * 8;
#pragma unroll
    for (int j = 0; j < 8; j++)
      kout[i][j] = f2bf(bf2f((unsigned short)xv[j]) * cf[j] +
                        sgn * bf2f((unsigned short)pv[j]) * sf[j]);
  }

  s16x8 aq[2][3];
#pragma unroll
  for (int rt = 0; rt < 2; rt++) {
#pragma unroll
    for (int c = 0; c < 3; c++) {
      const int row = w * 32 + rt * 16 + lrow;
      const int d0 = c * 32 + lq * 8;
      s16x8 fr = {};
      if (d0 < 80) {
        s16x8 xv = *(const s16x8*)&Y[row * 80 + d0];
        const int dp = (d0 < 40) ? d0 + 40 : d0 - 40;
        s16x8 pv = *(const s16x8*)&Y[row * 80 + dp];
        const float sgn = (d0 < 40) ? -1.f : 1.f;
        const float* cf = cosb + (size_t)(s0 + row) * 80 + d0;
        const float* sf = sinb + (size_t)(s0 + row) * 80 + d0;
#pragma unroll
        for (int j = 0; j < 8; j++)
          fr[j] = (short)f2bf(bf2f((unsigned short)xv[j]) * cf[j] +
                              sgn * bf2f((unsigned short)pv[j]) * sf[j]);
      }
      aq[rt][c] = fr;
    }
  }
  __syncthreads();  // B2

  // ---- write rope'd K at stride 104 (2-way bank aliasing = free) + zero pad ----
#pragma unroll
  for (int i = 0; i < 5; i++)
    *(int4*)&X[kro[i] * 104 + kco[i] * 8] = *(const int4*)kout[i];
  {
    const int r = t >> 1, wh = t & 1;
    const int4 z = {0, 0, 0, 0};
    *(int4*)&X[r * 104 + 80 + wh * 8] = z;
  }
  __syncthreads();  // B3

  // ---- QK^T: 2 row-tiles x 16 col-tiles, K = 96 ----
  fx4 acc2[2][16] = {};
#pragma unroll
  for (int c = 0; c < 3; c++) {
#pragma unroll
    for (int ct = 0; ct < 16; ct++) {
      s16x8 b = *(const s16x8*)&X[(ct * 16 + lrow) * 104 + c * 32 + lq * 8];
      acc2[0][ct] = mfma16(aq[0][c], b, acc2[0][ct]);
      acc2[1][ct] = mfma16(aq[1][c], b, acc2[1][ct]);
    }
  }

  // ---- softmax (rows wave-local: row = rt*16 + lq*4 + r) ----
  const float kscale = 0.11180339887498949f * 1.4426950408889634f;  // 80^-0.5 * log2e
  float inv[2][4];
#pragma unroll
  for (int rt = 0; rt < 2; rt++) {
    float mx[4] = {-1e30f, -1e30f, -1e30f, -1e30f};
#pragma unroll
    for (int ct = 0; ct < 16; ct++)
#pragma unroll
      for (int r = 0; r < 4; r++) mx[r] = fmaxf(mx[r], acc2[rt][ct][r]);
#pragma unroll
    for (int r = 0; r < 4; r++) {
      mx[r] = fmaxf(mx[r], __shfl_xor(mx[r], 1));
      mx[r] = fmaxf(mx[r], __shfl_xor(mx[r], 2));
      mx[r] = fmaxf(mx[r], __shfl_xor(mx[r], 4));
      mx[r] = fmaxf(mx[r], __shfl_xor(mx[r], 8));
    }
    float sm[4] = {0.f, 0.f, 0.f, 0.f};
#pragma unroll
    for (int ct = 0; ct < 16; ct++)
#pragma unroll
      for (int r = 0; r < 4; r++) {
        float e = exp2f((acc2[rt][ct][r] - mx[r]) * kscale);
        acc2[rt][ct][r] = e;
        sm[r] += e;
      }
#pragma unroll
    for (int r = 0; r < 4; r++) {
      sm[r] += __shfl_xor(sm[r], 1);
      sm[r] += __shfl_xor(sm[r], 2);
      sm[r] += __shfl_xor(sm[r], 4);
      sm[r] += __shfl_xor(sm[r], 8);
      inv[rt][r] = 1.f / sm[r];
    }
  }
  __syncthreads();  // B4: Ks dead; X becomes P-scratch

  // ---- V transpose: RV [256][80] -> Vt (Y) [80][264] ----
#pragma unroll
  for (int i = 0; i < 5; i++) {
    const int idx = t + i * 512;  // 2560 = 80 d-rows x 32 key-chunks
    const int d = idx >> 5, c = idx & 31;
    unsigned short o[8];
#pragma unroll
    for (int j = 0; j < 8; j++) o[j] = RV[(c * 8 + j) * 80 + d];
    *(int4*)&Y[d * 264 + c * 8] = *(const int4*)o;
  }

  // ---- P (rt=0) to per-wave scratch ----
  unsigned short* Pw = X + w * 4224;  // 16 rows x 264 elems
#pragma unroll
  for (int ct = 0; ct < 16; ct++)
#pragma unroll
    for (int r = 0; r < 4; r++)
      Pw[(lq * 4 + r) * 264 + ct * 16 + lrow] = f2bf(acc2[0][ct][r] * inv[0][r]);
  __syncthreads();  // B5: Vt complete before any PV b-read

  // ---- PV + output, two 16-row sweeps ----
#pragma unroll
  for (int rt = 0; rt < 2; rt++) {
    if (rt == 1) {
      // own-wave scratch reuse; within-wave LDS ordering via compiler waitcnt
#pragma unroll
      for (int ct = 0; ct < 16; ct++)
#pragma unroll
        for (int r = 0; r < 4; r++)
          Pw[(lq * 4 + r) * 264 + ct * 16 + lrow] = f2bf(acc2[1][ct][r] * inv[1][r]);
    }
    fx4 accO[5] = {};
#pragma unroll
    for (int kc = 0; kc < 8; kc++) {
      s16x8 a = *(const s16x8*)&Pw[lrow * 264 + kc * 32 + lq * 8];
#pragma unroll
      for (int tt = 0; tt < 5; tt++) {
        s16x8 b = *(const s16x8*)&Y[(tt * 16 + lrow) * 264 + kc * 32 + lq * 8];
        accO[tt] = mfma16(a, b, accO[tt]);
      }
    }
    const int srow = s0 + w * 32 + rt * 16 + lq * 4;
#pragma unroll
    for (int tt = 0; tt < 5; tt++) {
      const int col = h * 80 + tt * 16 + lrow;
#pragma unroll
      for (int r = 0; r < 4; r++)
        Ob[(size_t)(srow + r) * DIM + col] = f2bf(accO[tt][r]);
    }
  }
}

// ---------------- proj GEMM: 64x128 tiles for residency (~5 blocks/CU) ----------------
// C[m][n] = sum_k A[m][k]*Bt[n][k] + bias[n], f32 out. BK=64, XOR-8 chunk swizzle.
__global__ __launch_bounds__(256) void gemm_proj(const unsigned short* __restrict__ A,
                                                 const unsigned short* __restrict__ Bt,
                                                 const float* __restrict__ bias,
                                                 float* __restrict__ C,
                                                 int M, int N, int K) {
  __shared__ __attribute__((aligned(16))) unsigned short As[64 * 64];    // 8 KB
  __shared__ __attribute__((aligned(16))) unsigned short Bs[128 * 64];   // 16 KB
  const int tid = threadIdx.x;
  const int lane = tid & 63, w = tid >> 6;
  const int lrow = lane & 15, lq = lane >> 4;
  const int wm = w >> 1, wn = w & 1;  // wave tile 32x64
  const int m0 = blockIdx.y * 64, n0 = blockIdx.x * 128;

  // staging: slot s = i*256+tid; r = s>>3 = (tid>>3)+32i; chunk = (s&7)^(r&7) (const in i)
  const int tr = tid >> 3;
  const int scN = ((tid & 7) ^ (tr & 7)) * 8;
  const int l7 = lrow & 7;
  const int baseA = (wm * 32 + lrow) * 128;   // byte row base (8 chunks * 16B)
  const int baseB = (wn * 64 + lrow) * 128;

  fx4 acc[2][4] = {};

  for (int k0 = 0; k0 < K; k0 += 64) {
    __syncthreads();
#pragma unroll
    for (int i = 0; i < 2; i++)
      gload_lds16(A + (size_t)(m0 + tr + 32 * i) * K + k0 + scN,
                  (char*)As + i * 4096 + w * 1024);
#pragma unroll
    for (int i = 0; i < 4; i++)
      gload_lds16(Bt + (size_t)(n0 + tr + 32 * i) * K + k0 + scN,
                  (char*)Bs + i * 4096 + w * 1024);
    __syncthreads();

#pragma unroll
    for (int hh = 0; hh < 2; hh++) {
      const int xq = ((lq + hh * 4) ^ l7) * 16;
      s16x8 a[2], b[4];
#pragma unroll
      for (int i = 0; i < 2; i++) a[i] = *(const s16x8*)((char*)As + baseA + i * 2048 + xq);
#pragma unroll
      for (int j = 0; j < 4; j++) b[j] = *(const s16x8*)((char*)Bs + baseB + j * 2048 + xq);
#pragma unroll
      for (int i = 0; i < 2; i++)
#pragma unroll
        for (int j = 0; j < 4; j++)
          acc[i][j] = mfma16(a[i], b[j], acc[i][j]);
    }
  }

#pragma unroll
  for (int i = 0; i < 2; i++) {
    const int row_base = m0 + wm * 32 + i * 16 + lq * 4;
#pragma unroll
    for (int j = 0; j < 4; j++) {
      const int col = n0 + wn * 64 + j * 16 + lrow;
      const float bv = bias[col];
#pragma unroll
      for (int r = 0; r < 4; r++)
        C[(size_t)(row_base + r) * N + col] = acc[i][j][r] + bv;
    }
  }
}

// ---------------- launch ----------------
extern "C" void kernel_launch(void* const* d_in, const int* in_sizes, int n_in,
                              void* d_out, int out_size, void* d_ws, size_t ws_size,
                              hipStream_t stream) {
  const float* hidden = (const float*)d_in[0];
  // d_in[1] = cu_seqlens: fixed layout (32 chunks of 256), unused
  const float* cosb = (const float*)d_in[2];
  const float* sinb = (const float*)d_in[3];
  const float* w_qkv = (const float*)d_in[4];
  const float* b_qkv = (const float*)d_in[5];
  const float* w_proj = (const float*)d_in[6];
  const float* b_proj = (const float*)d_in[7];
  float* out = (float*)d_out;

  // workspace layout (bytes)
  char* ws = (char*)d_ws;
  constexpr size_t HB_B = (size_t)SEQ * DIM * 2;    // 20,971,520 hidden bf16
  constexpr size_t WQT_B = (size_t)NQKV * DIM * 2;  //  9,830,400 w_qkv^T bf16
  constexpr size_t WPT_B = (size_t)DIM * DIM * 2;   //  3,276,800 w_proj^T bf16
  constexpr size_t OB_B = (size_t)SEQ * DIM * 2;    // 20,971,520 attn out bf16
  size_t off = 0;
  unsigned short* hb = (unsigned short*)(ws + off);     off += HB_B;
  unsigned short* wqkvT = (unsigned short*)(ws + off);  off += WQT_B;
  unsigned short* wprojT = (unsigned short*)(ws + off); off += WPT_B;
  unsigned short* Ob = (unsigned short*)(ws + off);     off += OB_B;
  if (ws_size < off) return;

  // 1. cast hidden to bf16
  cast_bf16_kernel<<<dim3((SEQ * DIM / 4 + 255) / 256), dim3(256), 0, stream>>>(
      hidden, hb, SEQ * DIM / 4);
  // 2. transpose-cast weights
  transpose_cast_kernel<<<dim3(NQKV / 32, DIM / 32), dim3(256), 0, stream>>>(
      w_qkv, wqkvT, DIM, NQKV);
  transpose_cast_kernel<<<dim3(DIM / 32, DIM / 32), dim3(256), 0, stream>>>(
      w_proj, wprojT, DIM, DIM);
  // 3. mega: QKV GEMM + RoPE + attention -> Ob   (grid x=n for XCD A-panel sharing)
  mega_attn<<<dim3(NIMG, HEADS), dim3(512), 0, stream>>>(hb, wqkvT, b_qkv, cosb, sinb, Ob);
  // 4. proj GEMM (+bias) -> d_out (f32)
  gemm_proj<<<dim3(DIM / 128, SEQ / 64), dim3(256), 0, stream>>>(
      Ob, wprojT, b_proj, out, SEQ, DIM, DIM);
}

// Round 6
// 289.861 us; speedup vs baseline: 1.6497x; 1.0748x over previous
//
#include <hip/hip_runtime.h>
#include <stdint.h>

#define DEVFN __device__ __forceinline__

typedef short s16x8 __attribute__((ext_vector_type(8)));
typedef __bf16 bf16x8 __attribute__((ext_vector_type(8)));
typedef float fx4 __attribute__((ext_vector_type(4)));

// Problem constants (fixed by the reference)
constexpr int SEQ = 8192, DIM = 1280, HEADS = 16;
constexpr int NIMG = 32;
constexpr int NQKV = 3840;  // 3*DIM
constexpr int TS = 84;      // raw Q/K/V tile stride (168B rows: scatter = 2 lanes/bank, free)

DEVFN unsigned short f2bf(float f) {
  union { float f; unsigned u; } v; v.f = f;
  unsigned r = v.u + 0x7FFFu + ((v.u >> 16) & 1u);  // RNE
  return (unsigned short)(r >> 16);
}
DEVFN float bf2f(unsigned short u) {
  union { unsigned u; float f; } v; v.u = ((unsigned)u) << 16;
  return v.f;
}

DEVFN fx4 mfma16(s16x8 a, s16x8 b, fx4 c) {
  return __builtin_amdgcn_mfma_f32_16x16x32_bf16(
      __builtin_bit_cast(bf16x8, a), __builtin_bit_cast(bf16x8, b), c, 0, 0, 0);
}

DEVFN void gload_lds16(const void* g, void* l) {
  // global -> LDS direct, 16B per lane; LDS dest = wave-uniform base + lane*16
  __builtin_amdgcn_global_load_lds(
      (__attribute__((address_space(1))) void*)(uintptr_t)g,
      (__attribute__((address_space(3))) void*)l, 16, 0, 0);
}

// ---------------- f32 -> bf16 cast, 4 elems/thread ----------------
__global__ __launch_bounds__(256) void cast_bf16_kernel(const float* __restrict__ in,
                                                        unsigned short* __restrict__ out,
                                                        int n4) {
  int i = blockIdx.x * 256 + threadIdx.x;
  if (i >= n4) return;
  float4 v = ((const float4*)in)[i];
  ushort4 o;
  o.x = f2bf(v.x); o.y = f2bf(v.y); o.z = f2bf(v.z); o.w = f2bf(v.w);
  ((ushort4*)out)[i] = o;
}

// ---------------- transpose + cast: T[n][k] = W[k][n], bf16 out ----------------
__global__ __launch_bounds__(256) void transpose_cast_kernel(const float* __restrict__ W,
                                                             unsigned short* __restrict__ T,
                                                             int K, int N) {
  __shared__ float tile[32][33];
  const int tx = threadIdx.x & 31, ty = threadIdx.x >> 5;  // 32x8
  const int n0 = blockIdx.x * 32, k0 = blockIdx.y * 32;
#pragma unroll
  for (int i = 0; i < 4; i++) {
    int r = ty + i * 8;
    tile[r][tx] = W[(size_t)(k0 + r) * N + n0 + tx];
  }
  __syncthreads();
#pragma unroll
  for (int i = 0; i < 4; i++) {
    int r = ty + i * 8;
    T[(size_t)(n0 + r) * K + k0 + tx] = f2bf(tile[tx][r]);
  }
}

// ---------------- mega kernel: QKV GEMM + bias + RoPE + attention ----------------
// Block = (img n, head h), 512 threads = 8 waves (4x2). GEMM: 256x256x1280, BK=64,
// double-buffered LDS-DMA staging with raw-asm waitcnt+barrier (loads for k+1 in
// flight during compute k). Epilogue scatters acc+bias into stride-84 raw Q/K/V
// tiles; then rope + QK^T + softmax + PV as verified in rounds 4/5.
// LDS (153600 B): GEMM Abuf 2x32K @0, Bbuf 2x32K @65536 (dead after K-loop);
// X@0 (rawK84 -> Ks[256][104] -> P-scratch 8x16x264), Y@67584 (rawQ84 -> Vt[80][264]),
// RV@110592 (rawV84).
__global__ __launch_bounds__(512, 2) void mega_attn(const unsigned short* __restrict__ hb,
                                                    const unsigned short* __restrict__ wqkvT,
                                                    const float* __restrict__ b_qkv,
                                                    const float* __restrict__ cosb,
                                                    const float* __restrict__ sinb,
                                                    unsigned short* __restrict__ Ob) {
  __shared__ __attribute__((aligned(16))) char smem[153600];
  unsigned short* X = (unsigned short*)smem;
  unsigned short* Y = (unsigned short*)(smem + 67584);
  unsigned short* RV = (unsigned short*)(smem + 110592);
  char* Abuf = smem;          // 2 x 32768
  char* Bbuf = smem + 65536;  // 2 x 32768

  const int t = threadIdx.x;
  const int lane = t & 63, w = t >> 6;
  const int lrow = lane & 15, lq = lane >> 4;
  const int l7 = lrow & 7;
  const int n = blockIdx.x, h = blockIdx.y;
  const int s0 = n * 256;
  const int wm = w >> 1, wn = w & 1;

  // staging geometry: per matrix 2048 16B-chunks/iter; thread covers slots i*512+t.
  // slot s -> row r = s>>3 (= i*64 + (t>>3)); stored chunk t&7 holds global chunk
  // (t&7)^(r&7) (XOR-8 swizzle -> conflict-free ds_read_b128, measured r3).
  const int tr3 = t >> 3;
  const int cchunk = ((t & 7) ^ (tr3 & 7)) * 8;
  const unsigned short* pA = hb + (size_t)(s0 + tr3) * 1280 + cchunk;
  const unsigned short* pB[4];
#pragma unroll
  for (int i = 0; i < 4; i++) {
    const int r = i * 64 + tr3;
    const int rr = r < 240 ? r : 239;  // pad rows clamp (cols 240..255 never used)
    const int sgm = (rr >= 160) ? 2 : (rr >= 80 ? 1 : 0);
    pB[i] = wqkvT + (size_t)(sgm * DIM + h * 80 + (rr - sgm * 80)) * 1280 + cchunk;
  }

  int offA[4][2], offB[8][2];
#pragma unroll
  for (int i = 0; i < 4; i++) {
    const int ra = wm * 64 + i * 16 + lrow;
    offA[i][0] = ra * 128 + (lq ^ l7) * 16;
    offA[i][1] = ra * 128 + ((lq + 4) ^ l7) * 16;
  }
#pragma unroll
  for (int j = 0; j < 8; j++) {
    const int rb = wn * 128 + j * 16 + lrow;
    offB[j][0] = rb * 128 + (lq ^ l7) * 16;
    offB[j][1] = rb * 128 + ((lq + 4) ^ l7) * 16;
  }

  fx4 acc[4][8] = {};

  // prologue: stage k=0 into buf0
  {
    char* da = Abuf + w * 1024;
    char* db = Bbuf + w * 1024;
#pragma unroll
    for (int i = 0; i < 4; i++) {
      gload_lds16(pA + (size_t)i * 64 * 1280, da + i * 8192);
      gload_lds16(pB[i], db + i * 8192);
    }
  }

  for (int k = 0; k < 20; k++) {
    // drain own buf[k] loads, then barrier => everyone's buf[k] complete and
    // everyone finished reading buf[k&1] from iter k-2. Raw asm: no full
    // __syncthreads drain of the loads we issue below.
    asm volatile("s_waitcnt vmcnt(0)\n\ts_barrier" ::: "memory");
    if (k < 19) {  // issue buf[k+1] now; flies during compute(k)
      const int kof = (k + 1) * 64;
      char* da = Abuf + ((k + 1) & 1) * 32768 + w * 1024;
      char* db = Bbuf + ((k + 1) & 1) * 32768 + w * 1024;
#pragma unroll
      for (int i = 0; i < 4; i++) {
        gload_lds16(pA + (size_t)i * 64 * 1280 + kof, da + i * 8192);
        gload_lds16(pB[i] + kof, db + i * 8192);
      }
    }
    const char* As = Abuf + (k & 1) * 32768;
    const char* Bs = Bbuf + (k & 1) * 32768;
#pragma unroll
    for (int kq = 0; kq < 2; kq++) {
      s16x8 a[4], b[8];
#pragma unroll
      for (int i = 0; i < 4; i++) a[i] = *(const s16x8*)(As + offA[i][kq]);
#pragma unroll
      for (int j = 0; j < 8; j++) b[j] = *(const s16x8*)(Bs + offB[j][kq]);
#pragma unroll
      for (int i = 0; i < 4; i++)
#pragma unroll
        for (int j = 0; j < 8; j++)
          acc[i][j] = mfma16(a[i], b[j], acc[i][j]);
    }
  }
  __syncthreads();  // all fragment reads done before staging regions become Q/K/V

  // ---- epilogue scatter: acc + bias -> raw Q (Y), K (X), V (RV), stride 84 ----
#pragma unroll
  for (int j = 0; j < 8; j++) {
    const int col = wn * 128 + j * 16 + lrow;
    if (col < 240) {
      const int sgm = (col >= 160) ? 2 : (col >= 80 ? 1 : 0);
      const int d = col - sgm * 80;
      const float bv = b_qkv[sgm * DIM + h * 80 + d];
      unsigned short* dst = (sgm == 0) ? Y : (sgm == 1) ? X : RV;
#pragma unroll
      for (int i = 0; i < 4; i++) {
        const int row = wm * 64 + i * 16 + lq * 4;
#pragma unroll
        for (int r = 0; r < 4; r++)
          dst[(row + r) * TS + d] = f2bf(acc[i][j][r] + bv);
      }
    }
  }
  __syncthreads();  // B1: raw Q/K/V complete

  // ---- K rope -> regs; Q rope -> A-fragments (wave w owns q-rows w*32..w*32+31) ----
  unsigned short kout[5][8];
  int kro[5], kco[5];
#pragma unroll
  for (int i = 0; i < 5; i++) {
    const int idx = t + i * 512;
    const unsigned r = (unsigned)idx / 10u, c = (unsigned)idx % 10u;
    kro[i] = r; kco[i] = c;
    s16x8 xv = *(const s16x8*)&X[r * TS + c * 8];
    const unsigned cp = (c < 5) ? c + 5 : c - 5;  // partner chunk (+-40 elems)
    s16x8 pv = *(const s16x8*)&X[r * TS + cp * 8];
    const float sgn = (c < 5) ? -1.f : 1.f;
    const float* cf = cosb + (size_t)(s0 + r) * 80 + c * 8;
    const float* sf = sinb + (size_t)(s0 + r) * 80 + c * 8;
#pragma unroll
    for (int j = 0; j < 8; j++)
      kout[i][j] = f2bf(bf2f((unsigned short)xv[j]) * cf[j] +
                        sgn * bf2f((unsigned short)pv[j]) * sf[j]);
  }

  s16x8 aq[2][3];
#pragma unroll
  for (int rt = 0; rt < 2; rt++) {
#pragma unroll
    for (int c = 0; c < 3; c++) {
      const int row = w * 32 + rt * 16 + lrow;
      const int d0 = c * 32 + lq * 8;
      s16x8 fr = {};
      if (d0 < 80) {
        s16x8 xv = *(const s16x8*)&Y[row * TS + d0];
        const int dp = (d0 < 40) ? d0 + 40 : d0 - 40;
        s16x8 pv = *(const s16x8*)&Y[row * TS + dp];
        const float sgn = (d0 < 40) ? -1.f : 1.f;
        const float* cf = cosb + (size_t)(s0 + row) * 80 + d0;
        const float* sf = sinb + (size_t)(s0 + row) * 80 + d0;
#pragma unroll
        for (int j = 0; j < 8; j++)
          fr[j] = (short)f2bf(bf2f((unsigned short)xv[j]) * cf[j] +
                              sgn * bf2f((unsigned short)pv[j]) * sf[j]);
      }
      aq[rt][c] = fr;
    }
  }
  __syncthreads();  // B2

  // ---- write rope'd K at stride 104 (2-way bank aliasing = free) + zero pad ----
#pragma unroll
  for (int i = 0; i < 5; i++)
    *(int4*)&X[kro[i] * 104 + kco[i] * 8] = *(const int4*)kout[i];
  {
    const int r = t >> 1, wh = t & 1;
    const int4 z = {0, 0, 0, 0};
    *(int4*)&X[r * 104 + 80 + wh * 8] = z;
  }
  __syncthreads();  // B3

  // ---- QK^T: 2 row-tiles x 16 col-tiles, K = 96 ----
  fx4 acc2[2][16] = {};
#pragma unroll
  for (int c = 0; c < 3; c++) {
#pragma unroll
    for (int ct = 0; ct < 16; ct++) {
      s16x8 b = *(const s16x8*)&X[(ct * 16 + lrow) * 104 + c * 32 + lq * 8];
      acc2[0][ct] = mfma16(aq[0][c], b, acc2[0][ct]);
      acc2[1][ct] = mfma16(aq[1][c], b, acc2[1][ct]);
    }
  }

  // ---- softmax (rows wave-local: row = rt*16 + lq*4 + r) ----
  const float kscale = 0.11180339887498949f * 1.4426950408889634f;  // 80^-0.5 * log2e
  float inv[2][4];
#pragma unroll
  for (int rt = 0; rt < 2; rt++) {
    float mx[4] = {-1e30f, -1e30f, -1e30f, -1e30f};
#pragma unroll
    for (int ct = 0; ct < 16; ct++)
#pragma unroll
      for (int r = 0; r < 4; r++) mx[r] = fmaxf(mx[r], acc2[rt][ct][r]);
#pragma unroll
    for (int r = 0; r < 4; r++) {
      mx[r] = fmaxf(mx[r], __shfl_xor(mx[r], 1));
      mx[r] = fmaxf(mx[r], __shfl_xor(mx[r], 2));
      mx[r] = fmaxf(mx[r], __shfl_xor(mx[r], 4));
      mx[r] = fmaxf(mx[r], __shfl_xor(mx[r], 8));
    }
    float sm[4] = {0.f, 0.f, 0.f, 0.f};
#pragma unroll
    for (int ct = 0; ct < 16; ct++)
#pragma unroll
      for (int r = 0; r < 4; r++) {
        float e = exp2f((acc2[rt][ct][r] - mx[r]) * kscale);
        acc2[rt][ct][r] = e;
        sm[r] += e;
      }
#pragma unroll
    for (int r = 0; r < 4; r++) {
      sm[r] += __shfl_xor(sm[r], 1);
      sm[r] += __shfl_xor(sm[r], 2);
      sm[r] += __shfl_xor(sm[r], 4);
      sm[r] += __shfl_xor(sm[r], 8);
      inv[rt][r] = 1.f / sm[r];
    }
  }
  __syncthreads();  // B4: Ks dead; X becomes P-scratch

  // ---- V transpose: RV [256][84] -> Vt (Y) [80][264] ----
#pragma unroll
  for (int i = 0; i < 5; i++) {
    const int idx = t + i * 512;  // 2560 = 80 d-rows x 32 key-chunks
    const int d = idx >> 5, c = idx & 31;
    unsigned short o[8];
#pragma unroll
    for (int j = 0; j < 8; j++) o[j] = RV[(c * 8 + j) * TS + d];
    *(int4*)&Y[d * 264 + c * 8] = *(const int4*)o;
  }

  // ---- P (rt=0) to per-wave scratch ----
  unsigned short* Pw = X + w * 4224;  // 16 rows x 264 elems
#pragma unroll
  for (int ct = 0; ct < 16; ct++)
#pragma unroll
    for (int r = 0; r < 4; r++)
      Pw[(lq * 4 + r) * 264 + ct * 16 + lrow] = f2bf(acc2[0][ct][r] * inv[0][r]);
  __syncthreads();  // B5: Vt complete before any PV b-read

  // ---- PV + output, two 16-row sweeps ----
#pragma unroll
  for (int rt = 0; rt < 2; rt++) {
    if (rt == 1) {
#pragma unroll
      for (int ct = 0; ct < 16; ct++)
#pragma unroll
        for (int r = 0; r < 4; r++)
          Pw[(lq * 4 + r) * 264 + ct * 16 + lrow] = f2bf(acc2[1][ct][r] * inv[1][r]);
    }
    fx4 accO[5] = {};
#pragma unroll
    for (int kc = 0; kc < 8; kc++) {
      s16x8 a = *(const s16x8*)&Pw[lrow * 264 + kc * 32 + lq * 8];
#pragma unroll
      for (int tt = 0; tt < 5; tt++) {
        s16x8 b = *(const s16x8*)&Y[(tt * 16 + lrow) * 264 + kc * 32 + lq * 8];
        accO[tt] = mfma16(a, b, accO[tt]);
      }
    }
    const int srow = s0 + w * 32 + rt * 16 + lq * 4;
#pragma unroll
    for (int tt = 0; tt < 5; tt++) {
      const int col = h * 80 + tt * 16 + lrow;
#pragma unroll
      for (int r = 0; r < 4; r++)
        Ob[(size_t)(srow + r) * DIM + col] = f2bf(accO[tt][r]);
    }
  }
}

// ---------------- proj GEMM: 128x128, BK=64, register-prefetch pipeline ----------------
// Global->VGPR prefetch for tile k+1 flies during compute(k); __syncthreads drains it
// after it has already landed. Single-buffer LDS (32 KB) -> high residency.
// Grid: x = M-blocks (64), y = N-blocks (10); consecutive blocks stream distinct A
// panels once; whole w_projT (3.3 MB) is L2-resident per XCD.
__global__ __launch_bounds__(256) void gemm_proj(const unsigned short* __restrict__ A,
                                                 const unsigned short* __restrict__ Bt,
                                                 const float* __restrict__ bias,
                                                 float* __restrict__ C) {
  __shared__ __attribute__((aligned(16))) unsigned short As[128 * 64];  // 16 KB
  __shared__ __attribute__((aligned(16))) unsigned short Bs[128 * 64];  // 16 KB
  const int tid = threadIdx.x;
  const int lane = tid & 63, w = tid >> 6;
  const int lrow = lane & 15, lq = lane >> 4;
  const int l7 = lrow & 7;
  const int wm = w >> 1, wn = w & 1;  // 2x2 wave grid, 64x64 tiles
  const int m0 = blockIdx.x * 128, n0 = blockIdx.y * 128;

  // staging: per matrix 1024 chunks/iter; thread covers slots i*256+tid (i=0..3).
  // slot s -> r = s>>3 = i*32 + (tid>>3); stored chunk tid&7 = global (tid&7)^(r&7).
  const int tr3 = tid >> 3;
  const int cchunk = ((tid & 7) ^ (tr3 & 7)) * 8;
  const unsigned short* pA = A + (size_t)(m0 + tr3) * 1280 + cchunk;
  const unsigned short* pBt = Bt + (size_t)(n0 + tr3) * 1280 + cchunk;

  int offA[4][2], offB[4][2];
#pragma unroll
  for (int i = 0; i < 4; i++) {
    const int ra = wm * 64 + i * 16 + lrow;
    const int rb = wn * 64 + i * 16 + lrow;
    offA[i][0] = ra * 128 + (lq ^ l7) * 16;
    offA[i][1] = ra * 128 + ((lq + 4) ^ l7) * 16;
    offB[i][0] = rb * 128 + (lq ^ l7) * 16;
    offB[i][1] = rb * 128 + ((lq + 4) ^ l7) * 16;
  }

  s16x8 rga[4], rgb[4];
  auto LOADG = [&](int k) {
    const int kof = k * 64;
#pragma unroll
    for (int i = 0; i < 4; i++) {
      rga[i] = *(const s16x8*)(pA + (size_t)i * 32 * 1280 + kof);
      rgb[i] = *(const s16x8*)(pBt + (size_t)i * 32 * 1280 + kof);
    }
  };
  auto STOREL = [&]() {
#pragma unroll
    for (int i = 0; i < 4; i++) {
      *(s16x8*)((char*)As + i * 4096 + tid * 16) = rga[i];
      *(s16x8*)((char*)Bs + i * 4096 + tid * 16) = rgb[i];
    }
  };

  fx4 acc[4][4] = {};

  LOADG(0);
  STOREL();  // auto vmcnt wait on rga/rgb (prologue latency exposed once)
  __syncthreads();
  LOADG(1);  // flies during compute(0)

  for (int k = 0; k < 20; k++) {
#pragma unroll
    for (int kq = 0; kq < 2; kq++) {
      s16x8 a[4], b[4];
#pragma unroll
      for (int i = 0; i < 4; i++) a[i] = *(const s16x8*)((char*)As + offA[i][kq]);
#pragma unroll
      for (int j = 0; j < 4; j++) b[j] = *(const s16x8*)((char*)Bs + offB[j][kq]);
#pragma unroll
      for (int i = 0; i < 4; i++)
#pragma unroll
        for (int j = 0; j < 4; j++)
          acc[i][j] = mfma16(a[i], b[j], acc[i][j]);
    }
    if (k < 19) {
      __syncthreads();  // readers done with tile k; drains LOADG(k+1) (already landed)
      STOREL();         // regs(k+1) -> LDS
      __syncthreads();
      if (k < 18) LOADG(k + 2);  // flies during compute(k+1)
    }
  }

#pragma unroll
  for (int i = 0; i < 4; i++) {
    const int row_base = m0 + wm * 64 + i * 16 + lq * 4;
#pragma unroll
    for (int j = 0; j < 4; j++) {
      const int col = n0 + wn * 64 + j * 16 + lrow;
      const float bv = bias[col];
#pragma unroll
      for (int r = 0; r < 4; r++)
        C[(size_t)(row_base + r) * DIM + col] = acc[i][j][r] + bv;
    }
  }
}

// ---------------- launch ----------------
extern "C" void kernel_launch(void* const* d_in, const int* in_sizes, int n_in,
                              void* d_out, int out_size, void* d_ws, size_t ws_size,
                              hipStream_t stream) {
  const float* hidden = (const float*)d_in[0];
  // d_in[1] = cu_seqlens: fixed layout (32 chunks of 256), unused
  const float* cosb = (const float*)d_in[2];
  const float* sinb = (const float*)d_in[3];
  const float* w_qkv = (const float*)d_in[4];
  const float* b_qkv = (const float*)d_in[5];
  const float* w_proj = (const float*)d_in[6];
  const float* b_proj = (const float*)d_in[7];
  float* out = (float*)d_out;

  // workspace layout (bytes)
  char* ws = (char*)d_ws;
  constexpr size_t HB_B = (size_t)SEQ * DIM * 2;    // 20,971,520 hidden bf16
  constexpr size_t WQT_B = (size_t)NQKV * DIM * 2;  //  9,830,400 w_qkv^T bf16
  constexpr size_t WPT_B = (size_t)DIM * DIM * 2;   //  3,276,800 w_proj^T bf16
  constexpr size_t OB_B = (size_t)SEQ * DIM * 2;    // 20,971,520 attn out bf16
  size_t off = 0;
  unsigned short* hb = (unsigned short*)(ws + off);     off += HB_B;
  unsigned short* wqkvT = (unsigned short*)(ws + off);  off += WQT_B;
  unsigned short* wprojT = (unsigned short*)(ws + off); off += WPT_B;
  unsigned short* Ob = (unsigned short*)(ws + off);     off += OB_B;
  if (ws_size < off) return;

  // 1. cast hidden to bf16
  cast_bf16_kernel<<<dim3((SEQ * DIM / 4 + 255) / 256), dim3(256), 0, stream>>>(
      hidden, hb, SEQ * DIM / 4);
  // 2. transpose-cast weights
  transpose_cast_kernel<<<dim3(NQKV / 32, DIM / 32), dim3(256), 0, stream>>>(
      w_qkv, wqkvT, DIM, NQKV);
  transpose_cast_kernel<<<dim3(DIM / 32, DIM / 32), dim3(256), 0, stream>>>(
      w_proj, wprojT, DIM, DIM);
  // 3. mega: QKV GEMM + RoPE + attention -> Ob
  mega_attn<<<dim3(NIMG, HEADS), dim3(512), 0, stream>>>(hb, wqkvT, b_qkv, cosb, sinb, Ob);
  // 4. proj GEMM (+bias) -> d_out (f32)
  gemm_proj<<<dim3(SEQ / 128, DIM / 128), dim3(256), 0, stream>>>(
      Ob, wprojT, b_proj, out);
}